// Round 1
// baseline (175.087 us; speedup 1.0000x reference)
//
#include <hip/hip_runtime.h>
#include <math.h>

#define N_NODES 4096
#define DIM 256
#define NH 4
#define NG 16
#define LN_EPS 1e-5f
#define TEMP 5.0f
#define RSLACK 4160     // 4096 + 64 rows of slack for attention tile-tail reads
#define PS_STRIDE 72    // bf16 elems; 144 B row stride, 2-way aliasing only (free)
#define BS_STRIDE 264   // bf16 elems; 528 B row stride -> 2-way-free b128 reads
#define QT_MAX 24       // 24*16 = 384 max rows/graph
#define KC3 3           // 3-way key split (128 keys per split, 2 inner chunks)
#define ATTN_BLOCKS (NG * QT_MAX * KC3)  // 1152: block = 4 waves of (g,qt,h,kc)

typedef __attribute__((ext_vector_type(8))) short short8;
typedef __attribute__((ext_vector_type(4))) short short4_t;
typedef __attribute__((ext_vector_type(4))) float f32x4;

__device__ __forceinline__ unsigned short f2bf(float f) {
    unsigned u = __builtin_bit_cast(unsigned, f);
    u += 0x7FFFu + ((u >> 16) & 1u);  // RNE
    return (unsigned short)(u >> 16);
}
__device__ __forceinline__ float bf2f(unsigned short u) {
    return __builtin_bit_cast(float, (unsigned)u << 16);
}
__device__ __forceinline__ float fsigmoid(float z) { return 1.f / (1.f + __expf(-z)); }
__device__ __forceinline__ float ftanh(float z) {
    float t = __expf(2.f * z);
    return (t - 1.f) / (t + 1.f);
}
__device__ __forceinline__ int seg_search(const int* __restrict__ batch, int g) {
    int lo = 0, hi = N_NODES;
    while (lo < hi) {
        int mid = (lo + hi) >> 1;
        if (batch[mid] < g) lo = mid + 1; else hi = mid;
    }
    return lo;
}

// ================= K0: one-time conversions + graph prep =====================
// [0,16) segmax+gcw; 16 seg+cacc-zero; [17,81) x->bf16; [81,153) W^T bf16 tiles
__global__ __launch_bounds__(256) void k0_kernel(
    const float* __restrict__ x, const float* __restrict__ Wq,
    const float* __restrict__ Wk, const float* __restrict__ Wv,
    const float* __restrict__ Wv1, const float* __restrict__ Wc1,
    const int* __restrict__ batch,
    unsigned short* __restrict__ xb, unsigned short* __restrict__ WqT,
    unsigned short* __restrict__ WkT, unsigned short* __restrict__ WvT,
    unsigned short* __restrict__ Wv1T, unsigned short* __restrict__ Wc1aT,
    float* __restrict__ gcw, int* __restrict__ seg, float* __restrict__ cacc) {
    __shared__ float sred[1280];
    int id = blockIdx.x, tid = threadIdx.x;
    if (id < 16) {  // ---- segmax (4-way row split) + gcw dot for graph id ----
        int g = id;
        int s = seg_search(batch, g), e = seg_search(batch, g + 1);
        float* red = sred;          // [4][256]
        float* gl  = sred + 1024;   // [256]
        int c4 = (tid & 63) * 4, way = tid >> 6;
        float4 mx = {-INFINITY, -INFINITY, -INFINITY, -INFINITY};
        for (int i = s + way; i < e; i += 4) {
            float4 v = *(const float4*)&x[(size_t)i * DIM + c4];
            mx.x = fmaxf(mx.x, v.x); mx.y = fmaxf(mx.y, v.y);
            mx.z = fmaxf(mx.z, v.z); mx.w = fmaxf(mx.w, v.w);
        }
        *(float4*)&red[way * 256 + c4] = mx;
        __syncthreads();
        if (way == 0) {
#pragma unroll
            for (int j = 0; j < 4; ++j) {
                float mm = fmaxf(fmaxf(red[c4 + j], red[256 + c4 + j]),
                                 fmaxf(red[512 + c4 + j], red[768 + c4 + j]));
                gl[c4 + j] = bf2f(f2bf(mm));  // bf16-rounded (consistent precision)
            }
        }
        __syncthreads();
        float a0 = 0.f, a1 = 0.f, a2 = 0.f, a3 = 0.f;
        for (int k = 0; k < 256; k += 4) {
            a0 += gl[k + 0] * Wc1[(size_t)(256 + k + 0) * 256 + tid];
            a1 += gl[k + 1] * Wc1[(size_t)(256 + k + 1) * 256 + tid];
            a2 += gl[k + 2] * Wc1[(size_t)(256 + k + 2) * 256 + tid];
            a3 += gl[k + 3] * Wc1[(size_t)(256 + k + 3) * 256 + tid];
        }
        gcw[g * 256 + tid] = (a0 + a1) + (a2 + a3);
        return;
    }
    if (id == 16) {
        if (tid <= NG) seg[tid] = seg_search(batch, tid);
        for (int i = tid; i < N_NODES; i += 256) cacc[i] = 0.f;
        return;
    }
    if (id < 81) {  // ---- xb: bf16 copy of x, 64 rows/block ----
        int row = (id - 17) * 64 + (tid >> 2);
        int c0 = (tid & 3) * 64;
        const float* src = &x[(size_t)row * 256 + c0];
        unsigned short* dst = &xb[(size_t)row * 256 + c0];
#pragma unroll
        for (int j = 0; j < 8; ++j) {
            float4 a = *(const float4*)&src[j * 8];
            float4 b = *(const float4*)&src[j * 8 + 4];
            short8 r = {(short)f2bf(a.x), (short)f2bf(a.y), (short)f2bf(a.z), (short)f2bf(a.w),
                        (short)f2bf(b.x), (short)f2bf(b.y), (short)f2bf(b.z), (short)f2bf(b.w)};
            *(short8*)&dst[j * 8] = r;
        }
        return;
    }
    // ---- W^T bf16 tiles: WT[col][k] = bf16(W[k][col]); 64x64 tile/block ----
    int t = id - 81;
    const float* W; unsigned short* WT; int ncols, tt;
    if (t < 16)      { W = Wq;  WT = WqT;   ncols = 256; tt = t; }
    else if (t < 32) { W = Wk;  WT = WkT;   ncols = 256; tt = t - 16; }
    else if (t < 48) { W = Wv;  WT = WvT;   ncols = 256; tt = t - 32; }
    else if (t < 64) { W = Wc1; WT = Wc1aT; ncols = 256; tt = t - 48; }  // top half rows [0,256)
    else             { W = Wv1; WT = Wv1T;  ncols = 128; tt = t - 64; }
    int c0 = (ncols == 256) ? (tt & 3) * 64 : (tt & 1) * 64;
    int k0 = (ncols == 256) ? (tt >> 2) * 64 : (tt >> 1) * 64;
    int col = c0 + (tid >> 2);
    int kk0 = k0 + (tid & 3) * 16;
    short8 r0v, r1v;
#pragma unroll
    for (int kk = 0; kk < 8; ++kk)
        r0v[kk] = (short)f2bf(W[(size_t)(kk0 + kk) * ncols + col]);
#pragma unroll
    for (int kk = 0; kk < 8; ++kk)
        r1v[kk] = (short)f2bf(W[(size_t)(kk0 + 8 + kk) * ncols + col]);
    *(short8*)&WT[(size_t)col * 256 + kk0] = r0v;
    *(short8*)&WT[(size_t)col * 256 + kk0 + 8] = r1v;
}

// Stage a pre-transposed bf16 W tile (64 cols x 256 k) into padded LDS.
// Coalesced short8 global loads; ds_write_b128 is 2-way per 16-lane phase
// (free): bank-group = (col + chunk*4 + j) & 7 covers all 8 groups twice.
// Read path (BS_STRIDE=264) is byte-identical to the proven layout.
__device__ __forceinline__ void ldsB_bf(const unsigned short* __restrict__ WT, int bn,
                                        unsigned short* __restrict__ Bs) {
    const short8* src = (const short8*)&WT[(size_t)bn * 256 + threadIdx.x * 64];
    unsigned short* dst = &Bs[(threadIdx.x >> 2) * BS_STRIDE + (threadIdx.x & 3) * 64];
#pragma unroll
    for (int j = 0; j < 8; ++j) *(short8*)&dst[j * 8] = src[j];
    __syncthreads();
}

// ================= K1: Q/K/V GEMMs, Hv->vacc2, fused Tpre->cacc ==============
// [0,768) Q/K/V; [768,896) Hv; [896,1152) cacc (x@Wc1_top + bc1 + gcw -> tanh dot)
__global__ __launch_bounds__(256) void k1_kernel(
    const unsigned short* __restrict__ xb,
    const unsigned short* __restrict__ WqT, const unsigned short* __restrict__ WkT,
    const unsigned short* __restrict__ WvT, const unsigned short* __restrict__ Wv1T,
    const unsigned short* __restrict__ Wc1aT,
    const float* __restrict__ bq, const float* __restrict__ bk,
    const float* __restrict__ bv, const float* __restrict__ bv1,
    const float* __restrict__ Wv2, const float* __restrict__ bc1,
    const float* __restrict__ Wc2, const float* __restrict__ gcw,
    const int* __restrict__ batch,
    unsigned short* __restrict__ Qb, unsigned short* __restrict__ Kb,
    unsigned short* __restrict__ Vt, float* __restrict__ vacc2,
    float* __restrict__ cacc) {
    __shared__ __align__(16) unsigned short Bs[64 * BS_STRIDE];  // 33792 B
    int u = blockIdx.x, tid = threadIdx.x;
    int w = tid >> 6, lane = tid & 63, m = lane & 15, quad = lane >> 4;
    if (u < 768) {  // ---- Q/K/V ----
        int z = u >> 8, r = u & 255, bx = r & 63, by = r >> 6;
        const unsigned short* WT = (z == 0) ? WqT : (z == 1) ? WkT : WvT;
        const float* bias = (z == 0) ? bq : (z == 1) ? bk : bv;
        ldsB_bf(WT, by * 64, Bs);
        int rowA = bx * 64 + 16 * w + m;
        short8 a[8];
#pragma unroll
        for (int ks = 0; ks < 8; ++ks)
            a[ks] = *(const short8*)&xb[(size_t)rowA * 256 + ks * 32 + quad * 8];
        int node0 = bx * 64 + 16 * w + quad * 4;
#pragma unroll
        for (int nt = 0; nt < 4; ++nt) {
            f32x4 acc = {0.f, 0.f, 0.f, 0.f};
#pragma unroll
            for (int ks = 0; ks < 8; ++ks) {
                short8 b = *(const short8*)&Bs[(nt * 16 + m) * BS_STRIDE + ks * 32 + quad * 8];
                acc = __builtin_amdgcn_mfma_f32_16x16x32_bf16(a[ks], b, acc, 0, 0, 0);
            }
            int col = by * 64 + nt * 16 + m;
            float bb = bias[col];
            if (z == 0) {  // Q pre-scaled by 1/sqrt(64)
#pragma unroll
                for (int r2 = 0; r2 < 4; ++r2)
                    Qb[(size_t)(node0 + r2) * 256 + col] = f2bf((acc[r2] + bb) * 0.125f);
            } else if (z == 1) {
#pragma unroll
                for (int r2 = 0; r2 < 4; ++r2)
                    Kb[(size_t)(node0 + r2) * 256 + col] = f2bf(acc[r2] + bb);
            } else {
                short4_t pk = {(short)f2bf(acc[0] + bb), (short)f2bf(acc[1] + bb),
                               (short)f2bf(acc[2] + bb), (short)f2bf(acc[3] + bb)};
                *(short4_t*)&Vt[(size_t)col * RSLACK + node0] = pk;
            }
        }
    } else if (u < 896) {  // ---- Hv = relu(x@Wv1+bv1)·Wv2 -> vacc2 partial ----
        int r = u - 768, bx = r & 63, by = r >> 6;  // by in {0,1}
        ldsB_bf(Wv1T, by * 64, Bs);
        int rowA = bx * 64 + 16 * w + m;
        short8 a[8];
#pragma unroll
        for (int ks = 0; ks < 8; ++ks)
            a[ks] = *(const short8*)&xb[(size_t)rowA * 256 + ks * 32 + quad * 8];
        int node0 = bx * 64 + 16 * w + quad * 4;
        float psum[4] = {0.f, 0.f, 0.f, 0.f};
#pragma unroll
        for (int nt = 0; nt < 4; ++nt) {
            f32x4 acc = {0.f, 0.f, 0.f, 0.f};
#pragma unroll
            for (int ks = 0; ks < 8; ++ks) {
                short8 b = *(const short8*)&Bs[(nt * 16 + m) * BS_STRIDE + ks * 32 + quad * 8];
                acc = __builtin_amdgcn_mfma_f32_16x16x32_bf16(a[ks], b, acc, 0, 0, 0);
            }
            int col = by * 64 + nt * 16 + m;
            float bb = bv1[col], wv = Wv2[col];
#pragma unroll
            for (int r2 = 0; r2 < 4; ++r2) psum[r2] += fmaxf(acc[r2] + bb, 0.f) * wv;
        }
#pragma unroll
        for (int r2 = 0; r2 < 4; ++r2) {
#pragma unroll
            for (int mm = 1; mm < 16; mm <<= 1) psum[r2] += __shfl_xor(psum[r2], mm);
            if (m == 0) vacc2[(size_t)(node0 + r2) * 2 + by] = psum[r2];
        }
    } else {  // ---- fused: tanh(x@Wc1_top + bc1 + gcw[g]) · Wc2 -> cacc ----
        int r = u - 896, bx = r & 63, by = r >> 6;  // by in [0,4)
        ldsB_bf(Wc1aT, by * 64, Bs);
        int rowA = bx * 64 + 16 * w + m;
        short8 a[8];
#pragma unroll
        for (int ks = 0; ks < 8; ++ks)
            a[ks] = *(const short8*)&xb[(size_t)rowA * 256 + ks * 32 + quad * 8];
        int node0 = bx * 64 + 16 * w + quad * 4;
        int g0 = batch[node0], g1 = batch[node0 + 1];
        int g2 = batch[node0 + 2], g3 = batch[node0 + 3];
        float psum[4] = {0.f, 0.f, 0.f, 0.f};
#pragma unroll
        for (int nt = 0; nt < 4; ++nt) {
            f32x4 acc = {0.f, 0.f, 0.f, 0.f};
#pragma unroll
            for (int ks = 0; ks < 8; ++ks) {
                short8 b = *(const short8*)&Bs[(nt * 16 + m) * BS_STRIDE + ks * 32 + quad * 8];
                acc = __builtin_amdgcn_mfma_f32_16x16x32_bf16(a[ks], b, acc, 0, 0, 0);
            }
            int col = by * 64 + nt * 16 + m;
            float bb = bc1[col], wc = Wc2[col];
            const float* gc = &gcw[col];
            psum[0] += ftanh(acc[0] + bb + gc[g0 * 256]) * wc;
            psum[1] += ftanh(acc[1] + bb + gc[g1 * 256]) * wc;
            psum[2] += ftanh(acc[2] + bb + gc[g2 * 256]) * wc;
            psum[3] += ftanh(acc[3] + bb + gc[g3 * 256]) * wc;
        }
#pragma unroll
        for (int r2 = 0; r2 < 4; ++r2) {
#pragma unroll
            for (int mm = 1; mm < 16; mm <<= 1) psum[r2] += __shfl_xor(psum[r2], mm);
            if (m == 0) atomicAdd(&cacc[node0 + r2], psum[r2]);
        }
    }
}

// ================= K2: 3-way key-split attention =============================
__global__ __launch_bounds__(256) void k2_kernel(
    const unsigned short* __restrict__ Qb, const unsigned short* __restrict__ Kb,
    const unsigned short* __restrict__ Vt, const int* __restrict__ seg,
    unsigned short* __restrict__ Opart, float* __restrict__ Lpart) {
    __shared__ __align__(16) unsigned short Ps[4 * 16 * PS_STRIDE];
    int tid = threadIdx.x;
    int w = tid >> 6, lane = tid & 63, m = lane & 15, quad = lane >> 4;
    int wid = blockIdx.x * 4 + w;
    int g = wid / (KC3 * QT_MAX * NH);
    int r1 = wid - g * (KC3 * QT_MAX * NH);
    int kc = r1 / (QT_MAX * NH);
    int r2i = r1 - kc * (QT_MAX * NH);
    int qt = r2i >> 2, h = r2i & 3;
    int s = seg[g], e = seg[g + 1];
    int q0 = s + qt * 16;
    int kst = s + kc * 128;
    if (q0 >= e || kst >= e) return;
    int ken = min(e, kst + 128);

    short8 qa0 = *(const short8*)&Qb[(size_t)(q0 + m) * 256 + h * 64 + quad * 8];
    short8 qa1 = *(const short8*)&Qb[(size_t)(q0 + m) * 256 + h * 64 + 32 + quad * 8];
    short8 ones = {16256, 16256, 16256, 16256, 16256, 16256, 16256, 16256};  // bf16 1.0
    f32x4 O[4];
    f32x4 Lacc = {0.f, 0.f, 0.f, 0.f};
#pragma unroll
    for (int nt = 0; nt < 4; ++nt) O[nt] = (f32x4){0.f, 0.f, 0.f, 0.f};
    int wbase = w * 16 * PS_STRIDE;

    for (int k0 = kst; k0 < ken; k0 += 64) {
        f32x4 S[4];
#pragma unroll
        for (int nt = 0; nt < 4; ++nt) {
            int key = k0 + nt * 16 + m;
            short8 kb0 = *(const short8*)&Kb[(size_t)key * 256 + h * 64 + quad * 8];
            short8 kb1 = *(const short8*)&Kb[(size_t)key * 256 + h * 64 + 32 + quad * 8];
            f32x4 sa = {0.f, 0.f, 0.f, 0.f};
            sa = __builtin_amdgcn_mfma_f32_16x16x32_bf16(qa0, kb0, sa, 0, 0, 0);
            sa = __builtin_amdgcn_mfma_f32_16x16x32_bf16(qa1, kb1, sa, 0, 0, 0);
            S[nt] = sa;
        }
        __builtin_amdgcn_wave_barrier();  // don't sink LDS stores above prior reads
#pragma unroll
        for (int nt = 0; nt < 4; ++nt) {
            bool valid = (k0 + nt * 16 + m) < e;
#pragma unroll
            for (int r3 = 0; r3 < 4; ++r3) {
                float p = valid ? __expf(S[nt][r3]) : 0.f;  // Q pre-scaled; S bounded
                Ps[wbase + (quad * 4 + r3) * PS_STRIDE + nt * 16 + m] = f2bf(p);
            }
        }
        __builtin_amdgcn_wave_barrier();  // LDS write->read order (in-order DS pipe)
        short8 pa0 = *(const short8*)&Ps[wbase + m * PS_STRIDE + quad * 8];
        short8 pa1 = *(const short8*)&Ps[wbase + m * PS_STRIDE + 32 + quad * 8];
        Lacc = __builtin_amdgcn_mfma_f32_16x16x32_bf16(pa0, ones, Lacc, 0, 0, 0);
        Lacc = __builtin_amdgcn_mfma_f32_16x16x32_bf16(pa1, ones, Lacc, 0, 0, 0);
#pragma unroll
        for (int nt = 0; nt < 4; ++nt) {
            const unsigned short* vrow = &Vt[(size_t)(h * 64 + nt * 16 + m) * RSLACK + k0];
            short8 vb0 = *(const short8*)&vrow[quad * 8];
            short8 vb1 = *(const short8*)&vrow[32 + quad * 8];
            O[nt] = __builtin_amdgcn_mfma_f32_16x16x32_bf16(pa0, vb0, O[nt], 0, 0, 0);
            O[nt] = __builtin_amdgcn_mfma_f32_16x16x32_bf16(pa1, vb1, O[nt], 0, 0, 0);
        }
    }
#pragma unroll
    for (int r3 = 0; r3 < 4; ++r3) {
        int q = q0 + quad * 4 + r3;
        if (q < e) {
            if (m == 0) Lpart[((size_t)kc * N_NODES + q) * 4 + h] = Lacc[r3];
#pragma unroll
            for (int nt = 0; nt < 4; ++nt)
                Opart[((size_t)kc * N_NODES + q) * 256 + h * 64 + nt * 16 + m] =
                    f2bf(O[nt][r3]);
        }
    }
}

// ================= K3: w + graph softmax + combine + residual + LN ===========
// 512 blocks x 8 nodes; per-graph softmax stats computed once per block
__global__ __launch_bounds__(256) void k3_kernel(
    const unsigned short* __restrict__ Opart, const float* __restrict__ Lpart,
    const float* __restrict__ x, const float* __restrict__ vacc2,
    const float* __restrict__ cacc, const float* __restrict__ bv2,
    const float* __restrict__ bc2, const float* __restrict__ gamma,
    const float* __restrict__ beta, const int* __restrict__ batch,
    const int* __restrict__ seg, float* __restrict__ out,
    float* __restrict__ att_out) {
    __shared__ float wsc[776];
    __shared__ float gm[8], gsum[8];
    __shared__ float r1[4], r2[4];
    int tid = threadIdx.x;
    int n0 = blockIdx.x * 8;
    int gf = batch[n0], gl = batch[n0 + 7];
    int s0 = seg[gf], e1 = seg[gl + 1];
    float vb = bv2[0], cb = bc2[0];
    for (int j = s0 + tid; j < e1; j += 256) {
        float2 vv = *(const float2*)&vacc2[(size_t)j * 2];
        wsc[j - s0] = TEMP * (0.6f * fsigmoid(vv.x + vv.y + vb) +
                              0.3f * fsigmoid(cacc[j] + cb) + 0.1f / 4096.f);
    }
    __syncthreads();
    for (int g = gf; g <= gl; ++g) {
        int gs_ = seg[g], ge = seg[g + 1];
        float mx = -1e30f;
        for (int j = gs_ + tid; j < ge; j += 256) mx = fmaxf(mx, wsc[j - s0]);
#pragma unroll
        for (int k2 = 32; k2; k2 >>= 1) mx = fmaxf(mx, __shfl_xor(mx, k2));
        if ((tid & 63) == 0) r1[tid >> 6] = mx;
        __syncthreads();
        mx = fmaxf(fmaxf(r1[0], r1[1]), fmaxf(r1[2], r1[3]));
        float sm = 0.f;
        for (int j = gs_ + tid; j < ge; j += 256) sm += __expf(wsc[j - s0] - mx);
#pragma unroll
        for (int k2 = 32; k2; k2 >>= 1) sm += __shfl_xor(sm, k2);
        __syncthreads();
        if ((tid & 63) == 0) r2[tid >> 6] = sm;
        __syncthreads();
        if (tid == 0) {
            gm[g - gf] = mx;
            gsum[g - gf] = r2[0] + r2[1] + r2[2] + r2[3];
        }
        __syncthreads();
    }
    int h = tid >> 6;
    for (int i = 0; i < 8; ++i) {
        int n = n0 + i;
        int g = batch[n];
        int s = seg[g], e = seg[g + 1];
        float att_n = __expf(wsc[n - s0] - gm[g - gf]) / gsum[g - gf];
        if (tid == 0) att_out[n] = att_n;
        float L = 0.f, O = 0.f;
#pragma unroll
        for (int c = 0; c < KC3; ++c) {
            bool valid = (s + c * 128) < e;
            float lv = Lpart[((size_t)c * N_NODES + n) * 4 + h];
            float ov = bf2f(Opart[((size_t)c * N_NODES + n) * 256 + tid]);
            if (valid) { L += lv; O += ov; }
        }
        float o = (O / L) * att_n + x[(size_t)n * 256 + tid];
        float s1 = o, s2 = o * o;
#pragma unroll
        for (int k2 = 32; k2; k2 >>= 1) {
            s1 += __shfl_xor(s1, k2);
            s2 += __shfl_xor(s2, k2);
        }
        __syncthreads();  // protect r1/r2 reuse across iterations
        if ((tid & 63) == 0) { r1[tid >> 6] = s1; r2[tid >> 6] = s2; }
        __syncthreads();
        float mu = (r1[0] + r1[1] + r1[2] + r1[3]) * (1.f / 256.f);
        float ms = (r2[0] + r2[1] + r2[2] + r2[3]) * (1.f / 256.f);
        float rs = rsqrtf(ms - mu * mu + LN_EPS);
        out[(size_t)n * 256 + tid] = (o - mu) * rs * gamma[tid] + beta[tid];
    }
}

extern "C" void kernel_launch(void* const* d_in, const int* in_sizes, int n_in,
                              void* d_out, int out_size, void* d_ws, size_t ws_size,
                              hipStream_t stream) {
    const float* x     = (const float*)d_in[0];
    const float* Wq    = (const float*)d_in[1];
    const float* bq    = (const float*)d_in[2];
    const float* Wk    = (const float*)d_in[3];
    const float* bk    = (const float*)d_in[4];
    const float* Wv    = (const float*)d_in[5];
    const float* bv    = (const float*)d_in[6];
    const float* Wv1   = (const float*)d_in[7];
    const float* bv1   = (const float*)d_in[8];
    const float* Wv2   = (const float*)d_in[9];
    const float* bv2   = (const float*)d_in[10];
    const float* Wc1   = (const float*)d_in[11];
    const float* bc1   = (const float*)d_in[12];
    const float* Wc2   = (const float*)d_in[13];
    const float* bc2   = (const float*)d_in[14];
    const float* gamma = (const float*)d_in[15];
    const float* beta  = (const float*)d_in[16];
    const int*   batch = (const int*)d_in[17];

    float* out = (float*)d_out;        // [N, D]
    float* att = out + N_NODES * DIM;  // [N]

    // f32 region (cacc zeroed in k0; everything else written before read)
    float* vacc2 = (float*)d_ws;                        // 4096*2
    float* cacc  = vacc2 + N_NODES * 2;                 // 4096
    float* gcw   = cacc + N_NODES;                      // 16*256
    float* Lpart = gcw + NG * DIM;                      // 3*4096*4
    int*   seg   = (int*)(Lpart + KC3 * N_NODES * 4);   // 32 ints
    // bf16 region (all offsets 16B-aligned)
    unsigned short* xb    = (unsigned short*)(seg + 32);  // 4096*256
    unsigned short* WqT   = xb + N_NODES * DIM;           // 256*256
    unsigned short* WkT   = WqT + DIM * DIM;              // 256*256
    unsigned short* WvT   = WkT + DIM * DIM;              // 256*256
    unsigned short* Wc1aT = WvT + DIM * DIM;              // 256*256 (top half of Wc1)
    unsigned short* Wv1T  = Wc1aT + DIM * DIM;            // 128*256
    unsigned short* Qb    = Wv1T + (DIM / 2) * DIM;       // 4160*256
    unsigned short* Kb    = Qb + RSLACK * DIM;            // 4160*256
    unsigned short* Vt    = Kb + RSLACK * DIM;            // 256*4160
    unsigned short* Opart = Vt + DIM * RSLACK;            // 3*4096*256

    k0_kernel<<<153, 256, 0, stream>>>(x, Wq, Wk, Wv, Wv1, Wc1, batch,
                                       xb, WqT, WkT, WvT, Wv1T, Wc1aT,
                                       gcw, seg, cacc);
    k1_kernel<<<1152, 256, 0, stream>>>(xb, WqT, WkT, WvT, Wv1T, Wc1aT,
                                        bq, bk, bv, bv1, Wv2, bc1, Wc2, gcw, batch,
                                        Qb, Kb, Vt, vacc2, cacc);
    k2_kernel<<<ATTN_BLOCKS, 256, 0, stream>>>(Qb, Kb, Vt, seg, Opart, Lpart);
    k3_kernel<<<N_NODES / 8, 256, 0, stream>>>(Opart, Lpart, x, vacc2, cacc,
                                               bv2, bc2, gamma, beta, batch, seg,
                                               out, att);
}

// Round 2
// 167.056 us; speedup vs baseline: 1.0481x; 1.0481x over previous
//
#include <hip/hip_runtime.h>
#include <math.h>

#define N_NODES 4096
#define DIM 256
#define NH 4
#define NG 16
#define LN_EPS 1e-5f
#define TEMP 5.0f
#define RSLACK 4160     // 4096 + 64 rows of slack for attention tile-tail reads
#define PS_STRIDE 72    // bf16 elems; 144 B row stride, 2-way aliasing only (free)
#define BS_STRIDE 264   // bf16 elems; 528 B row stride -> 2-way-free b128 reads
#define QT_MAX 24       // 24*16 = 384 max rows/graph
#define K2_ATTN_BLOCKS (NG * QT_MAX)  // 384 blocks: wave = (g, qt, h), all keys

typedef __attribute__((ext_vector_type(8))) short short8;
typedef __attribute__((ext_vector_type(4))) short short4_t;
typedef __attribute__((ext_vector_type(4))) float f32x4;

__device__ __forceinline__ unsigned short f2bf(float f) {
    unsigned u = __builtin_bit_cast(unsigned, f);
    u += 0x7FFFu + ((u >> 16) & 1u);  // RNE
    return (unsigned short)(u >> 16);
}
__device__ __forceinline__ float bf2f(unsigned short u) {
    return __builtin_bit_cast(float, (unsigned)u << 16);
}
__device__ __forceinline__ float fsigmoid(float z) { return 1.f / (1.f + __expf(-z)); }
__device__ __forceinline__ float ftanh(float z) {
    float t = __expf(2.f * z);
    return (t - 1.f) / (t + 1.f);
}
__device__ __forceinline__ int seg_search(const int* __restrict__ batch, int g) {
    int lo = 0, hi = N_NODES;
    while (lo < hi) {
        int mid = (lo + hi) >> 1;
        if (batch[mid] < g) lo = mid + 1; else hi = mid;
    }
    return lo;
}

// A-fragment: 8 consecutive k of f32 x, cast bf16 in-register (same RNE values
// as a staged bf16 copy of x).
__device__ __forceinline__ short8 afrag_f32(const float* __restrict__ x, int row, int k0) {
    float4 a = *(const float4*)&x[(size_t)row * 256 + k0];
    float4 b = *(const float4*)&x[(size_t)row * 256 + k0 + 4];
    short8 r = {(short)f2bf(a.x), (short)f2bf(a.y), (short)f2bf(a.z), (short)f2bf(a.w),
                (short)f2bf(b.x), (short)f2bf(b.y), (short)f2bf(b.z), (short)f2bf(b.w)};
    return r;
}

// Cooperative 64-col W-tile load + transpose + bf16 cast into LDS: Bs[c][k].
__device__ __forceinline__ void ldsB(const float* __restrict__ W, int ws, int bn,
                                     unsigned short* __restrict__ Bs) {
    int c4 = (threadIdx.x & 15) * 4;
    int r0 = threadIdx.x >> 4;
    for (int p = 0; p < 16; ++p) {
        int k = p * 16 + r0;
        float4 wv = *(const float4*)&W[(size_t)k * ws + bn + c4];
        Bs[(c4 + 0) * BS_STRIDE + k] = f2bf(wv.x);
        Bs[(c4 + 1) * BS_STRIDE + k] = f2bf(wv.y);
        Bs[(c4 + 2) * BS_STRIDE + k] = f2bf(wv.z);
        Bs[(c4 + 3) * BS_STRIDE + k] = f2bf(wv.w);
    }
    __syncthreads();
}

// ================= K1: segmax+gcw, seg, Q/K/V GEMMs, Hv->vacc2, Tpre =========
// blocks [0,16) segmax+gcw; 16 seg; [17,785) Q/K/V; [785,913) Hv; [913,1169) Tpre
__global__ __launch_bounds__(256) void k1_kernel(
    const float* __restrict__ x,
    const float* __restrict__ Wq, const float* __restrict__ bq,
    const float* __restrict__ Wk, const float* __restrict__ bk,
    const float* __restrict__ Wv, const float* __restrict__ bv,
    const float* __restrict__ Wv1, const float* __restrict__ bv1,
    const float* __restrict__ Wv2, const float* __restrict__ Wc1,
    const float* __restrict__ bc1, const int* __restrict__ batch,
    unsigned short* __restrict__ Qb, unsigned short* __restrict__ Kb,
    unsigned short* __restrict__ Vt, float* __restrict__ vacc2,
    float* __restrict__ Tpre, float* __restrict__ gcw, int* __restrict__ seg) {
    __shared__ __align__(16) char smem[64 * BS_STRIDE * 2];  // 33792 B
    int id = blockIdx.x, tid = threadIdx.x;
    if (id < 16) {  // ---- segmax (4-way row split) + gcw dot for graph id ----
        int g = id;
        int s = seg_search(batch, g), e = seg_search(batch, g + 1);
        float* red = (float*)smem;          // [4][256]
        float* gl  = (float*)smem + 1024;   // [256]
        int c4 = (tid & 63) * 4, way = tid >> 6;
        float4 mx = {-INFINITY, -INFINITY, -INFINITY, -INFINITY};
#pragma unroll 8
        for (int i = s + way; i < e; i += 4) {
            float4 v = *(const float4*)&x[(size_t)i * DIM + c4];
            mx.x = fmaxf(mx.x, v.x); mx.y = fmaxf(mx.y, v.y);
            mx.z = fmaxf(mx.z, v.z); mx.w = fmaxf(mx.w, v.w);
        }
        *(float4*)&red[way * 256 + c4] = mx;
        __syncthreads();
        if (way == 0) {
#pragma unroll
            for (int j = 0; j < 4; ++j) {
                float mm = fmaxf(fmaxf(red[c4 + j], red[256 + c4 + j]),
                                 fmaxf(red[512 + c4 + j], red[768 + c4 + j]));
                gl[c4 + j] = bf2f(f2bf(mm));  // bf16-rounded (consistent precision)
            }
        }
        __syncthreads();
        // 32 loads in flight per batch -> 8 latency exposures instead of 64
        float ac[4] = {0.f, 0.f, 0.f, 0.f};
        for (int kb = 0; kb < 256; kb += 32) {
            float v[32];
#pragma unroll
            for (int j = 0; j < 32; ++j)
                v[j] = Wc1[(size_t)(256 + kb + j) * 256 + tid];
#pragma unroll
            for (int j = 0; j < 32; ++j) ac[j & 3] += gl[kb + j] * v[j];
        }
        gcw[g * 256 + tid] = (ac[0] + ac[1]) + (ac[2] + ac[3]);
        return;
    }
    if (id == 16) {
        if (tid <= NG) seg[tid] = seg_search(batch, tid);
        return;
    }
    int u = id - 17;
    unsigned short* Bs = (unsigned short*)smem;
    int w = tid >> 6, lane = tid & 63, m = lane & 15, quad = lane >> 4;
    if (u < 768) {  // ---- Q/K/V ----
        int z = u >> 8, r = u & 255, bx = r & 63, by = r >> 6;
        const float* W = (z == 0) ? Wq : (z == 1) ? Wk : Wv;
        const float* bias = (z == 0) ? bq : (z == 1) ? bk : bv;
        ldsB(W, 256, by * 64, Bs);
        int rowA = bx * 64 + 16 * w + m;
        short8 a[8];
#pragma unroll
        for (int ks = 0; ks < 8; ++ks) a[ks] = afrag_f32(x, rowA, ks * 32 + quad * 8);
        int node0 = bx * 64 + 16 * w + quad * 4;
#pragma unroll
        for (int nt = 0; nt < 4; ++nt) {
            f32x4 acc = {0.f, 0.f, 0.f, 0.f};
#pragma unroll
            for (int ks = 0; ks < 8; ++ks) {
                short8 b = *(const short8*)&Bs[(nt * 16 + m) * BS_STRIDE + ks * 32 + quad * 8];
                acc = __builtin_amdgcn_mfma_f32_16x16x32_bf16(a[ks], b, acc, 0, 0, 0);
            }
            int col = by * 64 + nt * 16 + m;
            float bb = bias[col];
            if (z == 0) {  // Q pre-scaled by 1/sqrt(64)
#pragma unroll
                for (int r2 = 0; r2 < 4; ++r2)
                    Qb[(size_t)(node0 + r2) * 256 + col] = f2bf((acc[r2] + bb) * 0.125f);
            } else if (z == 1) {
#pragma unroll
                for (int r2 = 0; r2 < 4; ++r2)
                    Kb[(size_t)(node0 + r2) * 256 + col] = f2bf(acc[r2] + bb);
            } else {
                short4_t pk = {(short)f2bf(acc[0] + bb), (short)f2bf(acc[1] + bb),
                               (short)f2bf(acc[2] + bb), (short)f2bf(acc[3] + bb)};
                *(short4_t*)&Vt[(size_t)col * RSLACK + node0] = pk;
            }
        }
    } else if (u < 896) {  // ---- Hv = relu(x@Wv1+bv1)·Wv2 -> vacc2 partial ----
        int r = u - 768, bx = r & 63, by = r >> 6;  // by in {0,1}
        ldsB(Wv1, 128, by * 64, Bs);
        int rowA = bx * 64 + 16 * w + m;
        short8 a[8];
#pragma unroll
        for (int ks = 0; ks < 8; ++ks) a[ks] = afrag_f32(x, rowA, ks * 32 + quad * 8);
        int node0 = bx * 64 + 16 * w + quad * 4;
        float psum[4] = {0.f, 0.f, 0.f, 0.f};
#pragma unroll
        for (int nt = 0; nt < 4; ++nt) {
            f32x4 acc = {0.f, 0.f, 0.f, 0.f};
#pragma unroll
            for (int ks = 0; ks < 8; ++ks) {
                short8 b = *(const short8*)&Bs[(nt * 16 + m) * BS_STRIDE + ks * 32 + quad * 8];
                acc = __builtin_amdgcn_mfma_f32_16x16x32_bf16(a[ks], b, acc, 0, 0, 0);
            }
            int col = by * 64 + nt * 16 + m;
            float bb = bv1[col], wv = Wv2[col];
#pragma unroll
            for (int r2 = 0; r2 < 4; ++r2) psum[r2] += fmaxf(acc[r2] + bb, 0.f) * wv;
        }
#pragma unroll
        for (int r2 = 0; r2 < 4; ++r2) {
#pragma unroll
            for (int mm = 1; mm < 16; mm <<= 1) psum[r2] += __shfl_xor(psum[r2], mm);
            if (m == 0) vacc2[(size_t)(node0 + r2) * 2 + by] = psum[r2];
        }
    } else {  // ---- Tpre = x@Wc1_top + bc1 (f32) ----
        int r = u - 896, bx = r & 63, by = r >> 6;  // by in [0,4)
        ldsB(Wc1, 256, by * 64, Bs);
        int rowA = bx * 64 + 16 * w + m;
        short8 a[8];
#pragma unroll
        for (int ks = 0; ks < 8; ++ks) a[ks] = afrag_f32(x, rowA, ks * 32 + quad * 8);
        int node0 = bx * 64 + 16 * w + quad * 4;
#pragma unroll
        for (int nt = 0; nt < 4; ++nt) {
            f32x4 acc = {0.f, 0.f, 0.f, 0.f};
#pragma unroll
            for (int ks = 0; ks < 8; ++ks) {
                short8 b = *(const short8*)&Bs[(nt * 16 + m) * BS_STRIDE + ks * 32 + quad * 8];
                acc = __builtin_amdgcn_mfma_f32_16x16x32_bf16(a[ks], b, acc, 0, 0, 0);
            }
            int col = by * 64 + nt * 16 + m;
            float bb = bc1[col];
#pragma unroll
            for (int r2 = 0; r2 < 4; ++r2)
                Tpre[(size_t)(node0 + r2) * 256 + col] = acc[r2] + bb;
        }
    }
}

// ================= K2: attention (all keys per wave) + cacc ==================
// blocks [0,384): wave = (g, qt, h) walks all key chunks; [384,640): cacc
__global__ __launch_bounds__(256) void k2_kernel(
    const float* __restrict__ Tpre, const float* __restrict__ gcw,
    const float* __restrict__ Wc2, const int* __restrict__ batch,
    const unsigned short* __restrict__ Qb, const unsigned short* __restrict__ Kb,
    const unsigned short* __restrict__ Vt, const int* __restrict__ seg,
    unsigned short* __restrict__ Opart, float* __restrict__ Lpart,
    float* __restrict__ cacc) {
    __shared__ __align__(16) unsigned short Ps[4 * 16 * PS_STRIDE];
    int tid = threadIdx.x;
    if (blockIdx.x >= K2_ATTN_BLOCKS) {  // ---- cacc: 16 nodes/block ----
        int id2 = blockIdx.x - K2_ATTN_BLOCKS;
        int nl = tid >> 4, cs = (tid & 15) * 16;
        int node = id2 * 16 + nl;
        int g = batch[node];
        float sum = 0.f;
#pragma unroll
        for (int j = 0; j < 16; ++j) {
            int c = cs + j;
            sum += ftanh(Tpre[(size_t)node * 256 + c] + gcw[g * 256 + c]) * Wc2[c];
        }
#pragma unroll
        for (int mm = 1; mm < 16; mm <<= 1) sum += __shfl_xor(sum, mm);
        if ((tid & 15) == 0) cacc[node] = sum;
        return;
    }
    // ---- attention: wave = (g, qt, h); loop over ALL key chunks of graph ----
    int w = tid >> 6, lane = tid & 63, m = lane & 15, quad = lane >> 4;
    int wid = blockIdx.x * 4 + w;
    int g = wid / (QT_MAX * NH);
    int r2i = wid - g * (QT_MAX * NH);
    int qt = r2i >> 2, h = r2i & 3;
    int s = seg[g], e = seg[g + 1];
    int q0 = s + qt * 16;
    if (q0 >= e) return;

    short8 qa0 = *(const short8*)&Qb[(size_t)(q0 + m) * 256 + h * 64 + quad * 8];
    short8 qa1 = *(const short8*)&Qb[(size_t)(q0 + m) * 256 + h * 64 + 32 + quad * 8];
    short8 ones = {16256, 16256, 16256, 16256, 16256, 16256, 16256, 16256};  // bf16 1.0
    f32x4 O[4];
    f32x4 Lacc = {0.f, 0.f, 0.f, 0.f};
#pragma unroll
    for (int nt = 0; nt < 4; ++nt) O[nt] = (f32x4){0.f, 0.f, 0.f, 0.f};
    int wbase = w * 16 * PS_STRIDE;

    for (int k0 = s; k0 < e; k0 += 64) {
        f32x4 S[4];
#pragma unroll
        for (int nt = 0; nt < 4; ++nt) {
            int key = k0 + nt * 16 + m;
            short8 kb0 = *(const short8*)&Kb[(size_t)key * 256 + h * 64 + quad * 8];
            short8 kb1 = *(const short8*)&Kb[(size_t)key * 256 + h * 64 + 32 + quad * 8];
            f32x4 sa = {0.f, 0.f, 0.f, 0.f};
            sa = __builtin_amdgcn_mfma_f32_16x16x32_bf16(qa0, kb0, sa, 0, 0, 0);
            sa = __builtin_amdgcn_mfma_f32_16x16x32_bf16(qa1, kb1, sa, 0, 0, 0);
            S[nt] = sa;
        }
        // hoist V loads above the Ps phase: latency hides under the exp VALU work
        short8 vb[4][2];
#pragma unroll
        for (int nt = 0; nt < 4; ++nt) {
            const unsigned short* vrow = &Vt[(size_t)(h * 64 + nt * 16 + m) * RSLACK + k0];
            vb[nt][0] = *(const short8*)&vrow[quad * 8];
            vb[nt][1] = *(const short8*)&vrow[32 + quad * 8];
        }
        __builtin_amdgcn_wave_barrier();  // don't sink LDS stores above prior reads
#pragma unroll
        for (int nt = 0; nt < 4; ++nt) {
            bool valid = (k0 + nt * 16 + m) < e;
#pragma unroll
            for (int r3 = 0; r3 < 4; ++r3) {
                float p = valid ? __expf(S[nt][r3]) : 0.f;  // Q pre-scaled; S bounded
                Ps[wbase + (quad * 4 + r3) * PS_STRIDE + nt * 16 + m] = f2bf(p);
            }
        }
        __builtin_amdgcn_wave_barrier();  // LDS write->read order (in-order DS pipe)
        short8 pa0 = *(const short8*)&Ps[wbase + m * PS_STRIDE + quad * 8];
        short8 pa1 = *(const short8*)&Ps[wbase + m * PS_STRIDE + 32 + quad * 8];
        Lacc = __builtin_amdgcn_mfma_f32_16x16x32_bf16(pa0, ones, Lacc, 0, 0, 0);
        Lacc = __builtin_amdgcn_mfma_f32_16x16x32_bf16(pa1, ones, Lacc, 0, 0, 0);
#pragma unroll
        for (int nt = 0; nt < 4; ++nt) {
            O[nt] = __builtin_amdgcn_mfma_f32_16x16x32_bf16(pa0, vb[nt][0], O[nt], 0, 0, 0);
            O[nt] = __builtin_amdgcn_mfma_f32_16x16x32_bf16(pa1, vb[nt][1], O[nt], 0, 0, 0);
        }
    }
#pragma unroll
    for (int r3 = 0; r3 < 4; ++r3) {
        int q = q0 + quad * 4 + r3;
        if (q < e) {
            if (m == 0) Lpart[(size_t)q * 4 + h] = Lacc[r3];
#pragma unroll
            for (int nt = 0; nt < 4; ++nt)
                Opart[(size_t)q * 256 + h * 64 + nt * 16 + m] = f2bf(O[nt][r3]);
        }
    }
}

// ================= K3: w + graph softmax + combine + residual + LN ===========
// 512 blocks x 8 nodes; per-graph softmax stats computed once per block
__global__ __launch_bounds__(256) void k3_kernel(
    const unsigned short* __restrict__ Opart, const float* __restrict__ Lpart,
    const float* __restrict__ x, const float* __restrict__ vacc2,
    const float* __restrict__ cacc, const float* __restrict__ bv2,
    const float* __restrict__ bc2, const float* __restrict__ gamma,
    const float* __restrict__ beta, const int* __restrict__ batch,
    const int* __restrict__ seg, float* __restrict__ out,
    float* __restrict__ att_out) {
    __shared__ float wsc[776];
    __shared__ float gm[8], gsum[8];
    __shared__ float r1[4], r2[4];
    int tid = threadIdx.x;
    int n0 = blockIdx.x * 8;
    int gf = batch[n0], gl = batch[n0 + 7];
    int s0 = seg[gf], e1 = seg[gl + 1];
    float vb = bv2[0], cb = bc2[0];
    for (int j = s0 + tid; j < e1; j += 256) {
        float2 vv = *(const float2*)&vacc2[(size_t)j * 2];
        wsc[j - s0] = TEMP * (0.6f * fsigmoid(vv.x + vv.y + vb) +
                              0.3f * fsigmoid(cacc[j] + cb) + 0.1f / 4096.f);
    }
    __syncthreads();
    for (int g = gf; g <= gl; ++g) {
        int gs_ = seg[g], ge = seg[g + 1];
        float mx = -1e30f;
        for (int j = gs_ + tid; j < ge; j += 256) mx = fmaxf(mx, wsc[j - s0]);
#pragma unroll
        for (int k2 = 32; k2; k2 >>= 1) mx = fmaxf(mx, __shfl_xor(mx, k2));
        if ((tid & 63) == 0) r1[tid >> 6] = mx;
        __syncthreads();
        mx = fmaxf(fmaxf(r1[0], r1[1]), fmaxf(r1[2], r1[3]));
        float sm = 0.f;
        for (int j = gs_ + tid; j < ge; j += 256) sm += __expf(wsc[j - s0] - mx);
#pragma unroll
        for (int k2 = 32; k2; k2 >>= 1) sm += __shfl_xor(sm, k2);
        __syncthreads();
        if ((tid & 63) == 0) r2[tid >> 6] = sm;
        __syncthreads();
        if (tid == 0) {
            gm[g - gf] = mx;
            gsum[g - gf] = r2[0] + r2[1] + r2[2] + r2[3];
        }
        __syncthreads();
    }
    int h = tid >> 6;
    for (int i = 0; i < 8; ++i) {
        int n = n0 + i;
        int g = batch[n];
        float att_n = __expf(wsc[n - s0] - gm[g - gf]) / gsum[g - gf];
        if (tid == 0) att_out[n] = att_n;
        float L = Lpart[(size_t)n * 4 + h];
        float O = bf2f(Opart[(size_t)n * 256 + tid]);
        float o = (O / L) * att_n + x[(size_t)n * 256 + tid];
        float s1 = o, s2 = o * o;
#pragma unroll
        for (int k2 = 32; k2; k2 >>= 1) {
            s1 += __shfl_xor(s1, k2);
            s2 += __shfl_xor(s2, k2);
        }
        __syncthreads();  // protect r1/r2 reuse across iterations
        if ((tid & 63) == 0) { r1[tid >> 6] = s1; r2[tid >> 6] = s2; }
        __syncthreads();
        float mu = (r1[0] + r1[1] + r1[2] + r1[3]) * (1.f / 256.f);
        float ms = (r2[0] + r2[1] + r2[2] + r2[3]) * (1.f / 256.f);
        float rs = rsqrtf(ms - mu * mu + LN_EPS);
        out[(size_t)n * 256 + tid] = (o - mu) * rs * gamma[tid] + beta[tid];
    }
}

extern "C" void kernel_launch(void* const* d_in, const int* in_sizes, int n_in,
                              void* d_out, int out_size, void* d_ws, size_t ws_size,
                              hipStream_t stream) {
    const float* x     = (const float*)d_in[0];
    const float* Wq    = (const float*)d_in[1];
    const float* bq    = (const float*)d_in[2];
    const float* Wk    = (const float*)d_in[3];
    const float* bk    = (const float*)d_in[4];
    const float* Wv    = (const float*)d_in[5];
    const float* bv    = (const float*)d_in[6];
    const float* Wv1   = (const float*)d_in[7];
    const float* bv1   = (const float*)d_in[8];
    const float* Wv2   = (const float*)d_in[9];
    const float* bv2   = (const float*)d_in[10];
    const float* Wc1   = (const float*)d_in[11];
    const float* bc1   = (const float*)d_in[12];
    const float* Wc2   = (const float*)d_in[13];
    const float* bc2   = (const float*)d_in[14];
    const float* gamma = (const float*)d_in[15];
    const float* beta  = (const float*)d_in[16];
    const int*   batch = (const int*)d_in[17];

    float* out = (float*)d_out;        // [N, D]
    float* att = out + N_NODES * DIM;  // [N]

    // f32 region (all written before read; no zeroing needed)
    float* vacc2 = (float*)d_ws;                        // 4096*2
    float* cacc  = vacc2 + N_NODES * 2;                 // 4096
    float* gcw   = cacc + N_NODES;                      // 16*256
    float* Lpart = gcw + NG * DIM;                      // 4096*4
    float* Tpre  = Lpart + N_NODES * 4;                 // 4096*256
    int*   seg   = (int*)(Tpre + N_NODES * DIM);        // 32 ints
    // bf16 region
    unsigned short* Qb    = (unsigned short*)(seg + 32);  // 4160*256
    unsigned short* Kb    = Qb + RSLACK * DIM;            // 4160*256
    unsigned short* Vt    = Kb + RSLACK * DIM;            // 256*4160
    unsigned short* Opart = Vt + DIM * RSLACK;            // 4096*256

    k1_kernel<<<1169, 256, 0, stream>>>(x, Wq, bq, Wk, bk, Wv, bv, Wv1, bv1, Wv2,
                                        Wc1, bc1, batch, Qb, Kb, Vt, vacc2, Tpre,
                                        gcw, seg);
    k2_kernel<<<K2_ATTN_BLOCKS + 256, 256, 0, stream>>>(Tpre, gcw, Wc2, batch,
                                                        Qb, Kb, Vt, seg,
                                                        Opart, Lpart, cacc);
    k3_kernel<<<N_NODES / 8, 256, 0, stream>>>(Opart, Lpart, x, vacc2, cacc,
                                               bv2, bc2, gamma, beta, batch, seg,
                                               out, att);
}

// Round 3
// 158.580 us; speedup vs baseline: 1.1041x; 1.0534x over previous
//
#include <hip/hip_runtime.h>
#include <math.h>

#define N_NODES 4096
#define DIM 256
#define NH 4
#define NG 16
#define LN_EPS 1e-5f
#define TEMP 5.0f
#define RSLACK 4160     // 4096 + 64 rows of slack for attention tile-tail reads
#define PS_STRIDE 72    // bf16 elems; 144 B row stride, 2-way aliasing only (free)
#define BS_STRIDE 264   // bf16 elems; 528 B row stride -> 2-way-free b128 reads
#define QT_MAX 24       // 24*16 = 384 max rows/graph
#define KC6 6           // 6-way key split: 64 keys per wave, ONE memory round
#define K2_ATTN_BLOCKS (NG * QT_MAX * KC6)  // 2304 = 8 XCD * 288 (2 graphs each)

typedef __attribute__((ext_vector_type(8))) short short8;
typedef __attribute__((ext_vector_type(4))) short short4_t;
typedef __attribute__((ext_vector_type(4))) float f32x4;

__device__ __forceinline__ unsigned short f2bf(float f) {
    unsigned u = __builtin_bit_cast(unsigned, f);
    u += 0x7FFFu + ((u >> 16) & 1u);  // RNE
    return (unsigned short)(u >> 16);
}
__device__ __forceinline__ float bf2f(unsigned short u) {
    return __builtin_bit_cast(float, (unsigned)u << 16);
}
__device__ __forceinline__ float fsigmoid(float z) { return 1.f / (1.f + __expf(-z)); }
__device__ __forceinline__ float ftanh(float z) {
    float t = __expf(2.f * z);
    return (t - 1.f) / (t + 1.f);
}
__device__ __forceinline__ int seg_search(const int* __restrict__ batch, int g) {
    int lo = 0, hi = N_NODES;
    while (lo < hi) {
        int mid = (lo + hi) >> 1;
        if (batch[mid] < g) lo = mid + 1; else hi = mid;
    }
    return lo;
}

// A-fragment: 8 consecutive k of f32 x, cast bf16 in-register (same RNE values
// as a staged bf16 copy of x).
__device__ __forceinline__ short8 afrag_f32(const float* __restrict__ x, int row, int k0) {
    float4 a = *(const float4*)&x[(size_t)row * 256 + k0];
    float4 b = *(const float4*)&x[(size_t)row * 256 + k0 + 4];
    short8 r = {(short)f2bf(a.x), (short)f2bf(a.y), (short)f2bf(a.z), (short)f2bf(a.w),
                (short)f2bf(b.x), (short)f2bf(b.y), (short)f2bf(b.z), (short)f2bf(b.w)};
    return r;
}

// Cooperative 64-col W-tile load + transpose + bf16 cast into LDS: Bs[c][k].
__device__ __forceinline__ void ldsB(const float* __restrict__ W, int ws, int bn,
                                     unsigned short* __restrict__ Bs) {
    int c4 = (threadIdx.x & 15) * 4;
    int r0 = threadIdx.x >> 4;
    for (int p = 0; p < 16; ++p) {
        int k = p * 16 + r0;
        float4 wv = *(const float4*)&W[(size_t)k * ws + bn + c4];
        Bs[(c4 + 0) * BS_STRIDE + k] = f2bf(wv.x);
        Bs[(c4 + 1) * BS_STRIDE + k] = f2bf(wv.y);
        Bs[(c4 + 2) * BS_STRIDE + k] = f2bf(wv.z);
        Bs[(c4 + 3) * BS_STRIDE + k] = f2bf(wv.w);
    }
    __syncthreads();
}

// ================= K1: segmax+gcw, seg, Q/K/V GEMMs, Hv->vacc2, Tpre =========
// blocks [0,16) segmax+gcw; 16 seg; [17,785) Q/K/V; [785,913) Hv; [913,1169) Tpre
__global__ __launch_bounds__(256) void k1_kernel(
    const float* __restrict__ x,
    const float* __restrict__ Wq, const float* __restrict__ bq,
    const float* __restrict__ Wk, const float* __restrict__ bk,
    const float* __restrict__ Wv, const float* __restrict__ bv,
    const float* __restrict__ Wv1, const float* __restrict__ bv1,
    const float* __restrict__ Wv2, const float* __restrict__ Wc1,
    const float* __restrict__ bc1, const int* __restrict__ batch,
    unsigned short* __restrict__ Qb, unsigned short* __restrict__ Kb,
    unsigned short* __restrict__ Vt, float* __restrict__ vacc2,
    float* __restrict__ Tpre, float* __restrict__ gcw, int* __restrict__ seg) {
    __shared__ __align__(16) char smem[64 * BS_STRIDE * 2];  // 33792 B
    int id = blockIdx.x, tid = threadIdx.x;
    if (id < 16) {  // ---- segmax (4-way row split) + gcw dot for graph id ----
        int g = id;
        int s = seg_search(batch, g), e = seg_search(batch, g + 1);
        float* red = (float*)smem;          // [4][256]
        float* gl  = (float*)smem + 1024;   // [256]
        int c4 = (tid & 63) * 4, way = tid >> 6;
        float4 mx = {-INFINITY, -INFINITY, -INFINITY, -INFINITY};
#pragma unroll 8
        for (int i = s + way; i < e; i += 4) {
            float4 v = *(const float4*)&x[(size_t)i * DIM + c4];
            mx.x = fmaxf(mx.x, v.x); mx.y = fmaxf(mx.y, v.y);
            mx.z = fmaxf(mx.z, v.z); mx.w = fmaxf(mx.w, v.w);
        }
        *(float4*)&red[way * 256 + c4] = mx;
        __syncthreads();
        if (way == 0) {
#pragma unroll
            for (int j = 0; j < 4; ++j) {
                float mm = fmaxf(fmaxf(red[c4 + j], red[256 + c4 + j]),
                                 fmaxf(red[512 + c4 + j], red[768 + c4 + j]));
                gl[c4 + j] = bf2f(f2bf(mm));  // bf16-rounded (consistent precision)
            }
        }
        __syncthreads();
        // 32 loads in flight per batch -> 8 latency exposures instead of 64
        float ac[4] = {0.f, 0.f, 0.f, 0.f};
        for (int kb = 0; kb < 256; kb += 32) {
            float v[32];
#pragma unroll
            for (int j = 0; j < 32; ++j)
                v[j] = Wc1[(size_t)(256 + kb + j) * 256 + tid];
#pragma unroll
            for (int j = 0; j < 32; ++j) ac[j & 3] += gl[kb + j] * v[j];
        }
        gcw[g * 256 + tid] = (ac[0] + ac[1]) + (ac[2] + ac[3]);
        return;
    }
    if (id == 16) {
        if (tid <= NG) seg[tid] = seg_search(batch, tid);
        return;
    }
    int u = id - 17;
    unsigned short* Bs = (unsigned short*)smem;
    int w = tid >> 6, lane = tid & 63, m = lane & 15, quad = lane >> 4;
    if (u < 768) {  // ---- Q/K/V ----
        int z = u >> 8, r = u & 255, bx = r & 63, by = r >> 6;
        const float* W = (z == 0) ? Wq : (z == 1) ? Wk : Wv;
        const float* bias = (z == 0) ? bq : (z == 1) ? bk : bv;
        ldsB(W, 256, by * 64, Bs);
        int rowA = bx * 64 + 16 * w + m;
        short8 a[8];
#pragma unroll
        for (int ks = 0; ks < 8; ++ks) a[ks] = afrag_f32(x, rowA, ks * 32 + quad * 8);
        int node0 = bx * 64 + 16 * w + quad * 4;
#pragma unroll
        for (int nt = 0; nt < 4; ++nt) {
            f32x4 acc = {0.f, 0.f, 0.f, 0.f};
#pragma unroll
            for (int ks = 0; ks < 8; ++ks) {
                short8 b = *(const short8*)&Bs[(nt * 16 + m) * BS_STRIDE + ks * 32 + quad * 8];
                acc = __builtin_amdgcn_mfma_f32_16x16x32_bf16(a[ks], b, acc, 0, 0, 0);
            }
            int col = by * 64 + nt * 16 + m;
            float bb = bias[col];
            if (z == 0) {  // Q pre-scaled by 1/sqrt(64)
#pragma unroll
                for (int r2 = 0; r2 < 4; ++r2)
                    Qb[(size_t)(node0 + r2) * 256 + col] = f2bf((acc[r2] + bb) * 0.125f);
            } else if (z == 1) {
#pragma unroll
                for (int r2 = 0; r2 < 4; ++r2)
                    Kb[(size_t)(node0 + r2) * 256 + col] = f2bf(acc[r2] + bb);
            } else {
                short4_t pk = {(short)f2bf(acc[0] + bb), (short)f2bf(acc[1] + bb),
                               (short)f2bf(acc[2] + bb), (short)f2bf(acc[3] + bb)};
                *(short4_t*)&Vt[(size_t)col * RSLACK + node0] = pk;
            }
        }
    } else if (u < 896) {  // ---- Hv = relu(x@Wv1+bv1)·Wv2 -> vacc2 partial ----
        int r = u - 768, bx = r & 63, by = r >> 6;  // by in {0,1}
        ldsB(Wv1, 128, by * 64, Bs);
        int rowA = bx * 64 + 16 * w + m;
        short8 a[8];
#pragma unroll
        for (int ks = 0; ks < 8; ++ks) a[ks] = afrag_f32(x, rowA, ks * 32 + quad * 8);
        int node0 = bx * 64 + 16 * w + quad * 4;
        float psum[4] = {0.f, 0.f, 0.f, 0.f};
#pragma unroll
        for (int nt = 0; nt < 4; ++nt) {
            f32x4 acc = {0.f, 0.f, 0.f, 0.f};
#pragma unroll
            for (int ks = 0; ks < 8; ++ks) {
                short8 b = *(const short8*)&Bs[(nt * 16 + m) * BS_STRIDE + ks * 32 + quad * 8];
                acc = __builtin_amdgcn_mfma_f32_16x16x32_bf16(a[ks], b, acc, 0, 0, 0);
            }
            int col = by * 64 + nt * 16 + m;
            float bb = bv1[col], wv = Wv2[col];
#pragma unroll
            for (int r2 = 0; r2 < 4; ++r2) psum[r2] += fmaxf(acc[r2] + bb, 0.f) * wv;
        }
#pragma unroll
        for (int r2 = 0; r2 < 4; ++r2) {
#pragma unroll
            for (int mm = 1; mm < 16; mm <<= 1) psum[r2] += __shfl_xor(psum[r2], mm);
            if (m == 0) vacc2[(size_t)(node0 + r2) * 2 + by] = psum[r2];
        }
    } else {  // ---- Tpre = x@Wc1_top + bc1 (f32) ----
        int r = u - 896, bx = r & 63, by = r >> 6;  // by in [0,4)
        ldsB(Wc1, 256, by * 64, Bs);
        int rowA = bx * 64 + 16 * w + m;
        short8 a[8];
#pragma unroll
        for (int ks = 0; ks < 8; ++ks) a[ks] = afrag_f32(x, rowA, ks * 32 + quad * 8);
        int node0 = bx * 64 + 16 * w + quad * 4;
#pragma unroll
        for (int nt = 0; nt < 4; ++nt) {
            f32x4 acc = {0.f, 0.f, 0.f, 0.f};
#pragma unroll
            for (int ks = 0; ks < 8; ++ks) {
                short8 b = *(const short8*)&Bs[(nt * 16 + m) * BS_STRIDE + ks * 32 + quad * 8];
                acc = __builtin_amdgcn_mfma_f32_16x16x32_bf16(a[ks], b, acc, 0, 0, 0);
            }
            int col = by * 64 + nt * 16 + m;
            float bb = bc1[col];
#pragma unroll
            for (int r2 = 0; r2 < 4; ++r2)
                Tpre[(size_t)(node0 + r2) * 256 + col] = acc[r2] + bb;
        }
    }
}

// ================= K2: attention (one 64-key chunk per wave) + cacc ==========
// blocks [0,2304): wave = (g, qt, kc, h), single chunk; [2304,2560): cacc
__global__ __launch_bounds__(256) void k2_kernel(
    const float* __restrict__ Tpre, const float* __restrict__ gcw,
    const float* __restrict__ Wc2, const int* __restrict__ batch,
    const unsigned short* __restrict__ Qb, const unsigned short* __restrict__ Kb,
    const unsigned short* __restrict__ Vt, const int* __restrict__ seg,
    unsigned short* __restrict__ Opart, float* __restrict__ Lpart,
    float* __restrict__ cacc) {
    __shared__ __align__(16) unsigned short Ps[4 * 16 * PS_STRIDE];
    int tid = threadIdx.x;
    if (blockIdx.x >= K2_ATTN_BLOCKS) {  // ---- cacc: 16 nodes/block ----
        int id2 = blockIdx.x - K2_ATTN_BLOCKS;
        int nl = tid >> 4, cs = (tid & 15) * 16;
        int node = id2 * 16 + nl;
        int g = batch[node];
        float sum = 0.f;
#pragma unroll
        for (int j = 0; j < 16; ++j) {
            int c = cs + j;
            sum += ftanh(Tpre[(size_t)node * 256 + c] + gcw[g * 256 + c]) * Wc2[c];
        }
#pragma unroll
        for (int mm = 1; mm < 16; mm <<= 1) sum += __shfl_xor(sum, mm);
        if ((tid & 15) == 0) cacc[node] = sum;
        return;
    }
    // ---- attention: wave = (g, qt, kc, h); ONE 64-key chunk, one mem round ----
    // XCD-aware bijective swizzle: 2304 = 8 * 288; 288 blocks = 2 graphs' work,
    // so each XCD's L2 holds only ~2 graphs of K/V/Q (L2-resident after 1 fetch).
    int bid = (blockIdx.x & 7) * (K2_ATTN_BLOCKS / 8) + (blockIdx.x >> 3);
    int w = tid >> 6, lane = tid & 63, m = lane & 15, quad = lane >> 4;
    int g = bid / (QT_MAX * KC6);
    int r1 = bid - g * (QT_MAX * KC6);
    int kc = r1 / QT_MAX;          // qt innermost: consecutive bids share K chunk
    int qt = r1 - kc * QT_MAX;
    int h = w;
    int s = seg[g], e = seg[g + 1];
    int q0 = s + qt * 16;
    int kst = s + kc * 64;
    if (q0 >= e || kst >= e) return;

    // ---- issue ALL loads up front: Q(2) + K(8) + V(8), one latency round ----
    short8 qa0 = *(const short8*)&Qb[(size_t)(q0 + m) * 256 + h * 64 + quad * 8];
    short8 qa1 = *(const short8*)&Qb[(size_t)(q0 + m) * 256 + h * 64 + 32 + quad * 8];
    short8 kb[4][2], vb[4][2];
#pragma unroll
    for (int nt = 0; nt < 4; ++nt) {
        int key = kst + nt * 16 + m;
        kb[nt][0] = *(const short8*)&Kb[(size_t)key * 256 + h * 64 + quad * 8];
        kb[nt][1] = *(const short8*)&Kb[(size_t)key * 256 + h * 64 + 32 + quad * 8];
    }
#pragma unroll
    for (int nt = 0; nt < 4; ++nt) {
        const unsigned short* vrow = &Vt[(size_t)(h * 64 + nt * 16 + m) * RSLACK + kst];
        vb[nt][0] = *(const short8*)&vrow[quad * 8];
        vb[nt][1] = *(const short8*)&vrow[32 + quad * 8];
    }

    f32x4 S[4];
#pragma unroll
    for (int nt = 0; nt < 4; ++nt) {
        f32x4 sa = {0.f, 0.f, 0.f, 0.f};
        sa = __builtin_amdgcn_mfma_f32_16x16x32_bf16(qa0, kb[nt][0], sa, 0, 0, 0);
        sa = __builtin_amdgcn_mfma_f32_16x16x32_bf16(qa1, kb[nt][1], sa, 0, 0, 0);
        S[nt] = sa;
    }
#pragma unroll
    for (int nt = 0; nt < 4; ++nt) {
        bool valid = (kst + nt * 16 + m) < e;
#pragma unroll
        for (int r3 = 0; r3 < 4; ++r3) {
            float p = valid ? __expf(S[nt][r3]) : 0.f;  // Q pre-scaled; S bounded
            Ps[w * 16 * PS_STRIDE + (quad * 4 + r3) * PS_STRIDE + nt * 16 + m] = f2bf(p);
        }
    }
    __builtin_amdgcn_wave_barrier();  // LDS write->read order (in-order DS pipe)
    short8 pa0 = *(const short8*)&Ps[w * 16 * PS_STRIDE + m * PS_STRIDE + quad * 8];
    short8 pa1 = *(const short8*)&Ps[w * 16 * PS_STRIDE + m * PS_STRIDE + 32 + quad * 8];
    short8 ones = {16256, 16256, 16256, 16256, 16256, 16256, 16256, 16256};  // bf16 1.0
    f32x4 Lacc = {0.f, 0.f, 0.f, 0.f};
    Lacc = __builtin_amdgcn_mfma_f32_16x16x32_bf16(pa0, ones, Lacc, 0, 0, 0);
    Lacc = __builtin_amdgcn_mfma_f32_16x16x32_bf16(pa1, ones, Lacc, 0, 0, 0);
    f32x4 O[4];
#pragma unroll
    for (int nt = 0; nt < 4; ++nt) {
        f32x4 oa = {0.f, 0.f, 0.f, 0.f};
        oa = __builtin_amdgcn_mfma_f32_16x16x32_bf16(pa0, vb[nt][0], oa, 0, 0, 0);
        oa = __builtin_amdgcn_mfma_f32_16x16x32_bf16(pa1, vb[nt][1], oa, 0, 0, 0);
        O[nt] = oa;
    }
#pragma unroll
    for (int r3 = 0; r3 < 4; ++r3) {
        int q = q0 + quad * 4 + r3;
        if (q < e) {
            if (m == 0) Lpart[((size_t)kc * N_NODES + q) * 4 + h] = Lacc[r3];
#pragma unroll
            for (int nt = 0; nt < 4; ++nt)
                Opart[((size_t)kc * N_NODES + q) * 256 + h * 64 + nt * 16 + m] =
                    f2bf(O[nt][r3]);
        }
    }
}

// ================= K3: w + graph softmax + combine + residual + LN ===========
// 512 blocks x 8 nodes; per-graph softmax stats computed once per block
__global__ __launch_bounds__(256) void k3_kernel(
    const unsigned short* __restrict__ Opart, const float* __restrict__ Lpart,
    const float* __restrict__ x, const float* __restrict__ vacc2,
    const float* __restrict__ cacc, const float* __restrict__ bv2,
    const float* __restrict__ bc2, const float* __restrict__ gamma,
    const float* __restrict__ beta, const int* __restrict__ batch,
    const int* __restrict__ seg, float* __restrict__ out,
    float* __restrict__ att_out) {
    __shared__ float wsc[776];
    __shared__ float gm[8], gsum[8];
    __shared__ float r1[4], r2[4];
    int tid = threadIdx.x;
    int n0 = blockIdx.x * 8;
    int gf = batch[n0], gl = batch[n0 + 7];
    int s0 = seg[gf], e1 = seg[gl + 1];
    float vb = bv2[0], cb = bc2[0];
    for (int j = s0 + tid; j < e1; j += 256) {
        float2 vv = *(const float2*)&vacc2[(size_t)j * 2];
        wsc[j - s0] = TEMP * (0.6f * fsigmoid(vv.x + vv.y + vb) +
                              0.3f * fsigmoid(cacc[j] + cb) + 0.1f / 4096.f);
    }
    __syncthreads();
    for (int g = gf; g <= gl; ++g) {
        int gs_ = seg[g], ge = seg[g + 1];
        float mx = -1e30f;
        for (int j = gs_ + tid; j < ge; j += 256) mx = fmaxf(mx, wsc[j - s0]);
#pragma unroll
        for (int k2 = 32; k2; k2 >>= 1) mx = fmaxf(mx, __shfl_xor(mx, k2));
        if ((tid & 63) == 0) r1[tid >> 6] = mx;
        __syncthreads();
        mx = fmaxf(fmaxf(r1[0], r1[1]), fmaxf(r1[2], r1[3]));
        float sm = 0.f;
        for (int j = gs_ + tid; j < ge; j += 256) sm += __expf(wsc[j - s0] - mx);
#pragma unroll
        for (int k2 = 32; k2; k2 >>= 1) sm += __shfl_xor(sm, k2);
        __syncthreads();
        if ((tid & 63) == 0) r2[tid >> 6] = sm;
        __syncthreads();
        if (tid == 0) {
            gm[g - gf] = mx;
            gsum[g - gf] = r2[0] + r2[1] + r2[2] + r2[3];
        }
        __syncthreads();
    }
    int h = tid >> 6;
    for (int i = 0; i < 8; ++i) {
        int n = n0 + i;
        int g = batch[n];
        int s = seg[g], e = seg[g + 1];
        float att_n = __expf(wsc[n - s0] - gm[g - gf]) / gsum[g - gf];
        if (tid == 0) att_out[n] = att_n;
        float L = 0.f, O = 0.f;
#pragma unroll
        for (int c = 0; c < KC6; ++c) {
            bool valid = (s + c * 64) < e;
            float lv = Lpart[((size_t)c * N_NODES + n) * 4 + h];
            float ov = bf2f(Opart[((size_t)c * N_NODES + n) * 256 + tid]);
            if (valid) { L += lv; O += ov; }
        }
        float o = (O / L) * att_n + x[(size_t)n * 256 + tid];
        float s1 = o, s2 = o * o;
#pragma unroll
        for (int k2 = 32; k2; k2 >>= 1) {
            s1 += __shfl_xor(s1, k2);
            s2 += __shfl_xor(s2, k2);
        }
        __syncthreads();  // protect r1/r2 reuse across iterations
        if ((tid & 63) == 0) { r1[tid >> 6] = s1; r2[tid >> 6] = s2; }
        __syncthreads();
        float mu = (r1[0] + r1[1] + r1[2] + r1[3]) * (1.f / 256.f);
        float ms = (r2[0] + r2[1] + r2[2] + r2[3]) * (1.f / 256.f);
        float rs = rsqrtf(ms - mu * mu + LN_EPS);
        out[(size_t)n * 256 + tid] = (o - mu) * rs * gamma[tid] + beta[tid];
    }
}

extern "C" void kernel_launch(void* const* d_in, const int* in_sizes, int n_in,
                              void* d_out, int out_size, void* d_ws, size_t ws_size,
                              hipStream_t stream) {
    const float* x     = (const float*)d_in[0];
    const float* Wq    = (const float*)d_in[1];
    const float* bq    = (const float*)d_in[2];
    const float* Wk    = (const float*)d_in[3];
    const float* bk    = (const float*)d_in[4];
    const float* Wv    = (const float*)d_in[5];
    const float* bv    = (const float*)d_in[6];
    const float* Wv1   = (const float*)d_in[7];
    const float* bv1   = (const float*)d_in[8];
    const float* Wv2   = (const float*)d_in[9];
    const float* bv2   = (const float*)d_in[10];
    const float* Wc1   = (const float*)d_in[11];
    const float* bc1   = (const float*)d_in[12];
    const float* Wc2   = (const float*)d_in[13];
    const float* bc2   = (const float*)d_in[14];
    const float* gamma = (const float*)d_in[15];
    const float* beta  = (const float*)d_in[16];
    const int*   batch = (const int*)d_in[17];

    float* out = (float*)d_out;        // [N, D]
    float* att = out + N_NODES * DIM;  // [N]

    // f32 region (all written before read; no zeroing needed)
    float* vacc2 = (float*)d_ws;                        // 4096*2
    float* cacc  = vacc2 + N_NODES * 2;                 // 4096
    float* gcw   = cacc + N_NODES;                      // 16*256
    float* Lpart = gcw + NG * DIM;                      // 6*4096*4
    float* Tpre  = Lpart + KC6 * N_NODES * 4;           // 4096*256
    int*   seg   = (int*)(Tpre + N_NODES * DIM);        // 32 ints
    // bf16 region
    unsigned short* Qb    = (unsigned short*)(seg + 32);  // 4160*256
    unsigned short* Kb    = Qb + RSLACK * DIM;            // 4160*256
    unsigned short* Vt    = Kb + RSLACK * DIM;            // 256*4160
    unsigned short* Opart = Vt + DIM * RSLACK;            // 6*4096*256

    k1_kernel<<<1169, 256, 0, stream>>>(x, Wq, bq, Wk, bk, Wv, bv, Wv1, bv1, Wv2,
                                        Wc1, bc1, batch, Qb, Kb, Vt, vacc2, Tpre,
                                        gcw, seg);
    k2_kernel<<<K2_ATTN_BLOCKS + 256, 256, 0, stream>>>(Tpre, gcw, Wc2, batch,
                                                        Qb, Kb, Vt, seg,
                                                        Opart, Lpart, cacc);
    k3_kernel<<<N_NODES / 8, 256, 0, stream>>>(Opart, Lpart, x, vacc2, cacc,
                                               bv2, bc2, gamma, beta, batch, seg,
                                               out, att);
}

// Round 4
// 141.135 us; speedup vs baseline: 1.2406x; 1.1236x over previous
//
#include <hip/hip_runtime.h>
#include <math.h>

#define N_NODES 4096
#define DIM 256
#define NH 4
#define NG 16
#define LN_EPS 1e-5f
#define TEMP 5.0f
#define RSLACK 4160     // 4096 + 64 rows of slack for attention tile-tail reads
#define PS_STRIDE 72    // bf16 elems; 144 B row stride, 2-way aliasing only (free)
#define BS_STRIDE 264   // bf16 elems; 528 B row stride -> 2-way-free b128 reads
#define QP_MAX 12       // 12*32 = 384 max rows/graph (qp covers 32 q rows)
#define K2_ATTN_BLOCKS (NG * QP_MAX)  // 192 blocks = 8 XCD * (2 graphs * 12 qp)

typedef __attribute__((ext_vector_type(8))) short short8;
typedef __attribute__((ext_vector_type(4))) short short4_t;
typedef __attribute__((ext_vector_type(4))) float f32x4;

__device__ __forceinline__ unsigned short f2bf(float f) {
    unsigned u = __builtin_bit_cast(unsigned, f);
    u += 0x7FFFu + ((u >> 16) & 1u);  // RNE
    return (unsigned short)(u >> 16);
}
__device__ __forceinline__ float bf2f(unsigned short u) {
    return __builtin_bit_cast(float, (unsigned)u << 16);
}
__device__ __forceinline__ float fsigmoid(float z) { return 1.f / (1.f + __expf(-z)); }
__device__ __forceinline__ float ftanh(float z) {
    float t = __expf(2.f * z);
    return (t - 1.f) / (t + 1.f);
}
__device__ __forceinline__ int seg_search(const int* __restrict__ batch, int g) {
    int lo = 0, hi = N_NODES;
    while (lo < hi) {
        int mid = (lo + hi) >> 1;
        if (batch[mid] < g) lo = mid + 1; else hi = mid;
    }
    return lo;
}

// A-fragment: 8 consecutive k of f32 x, cast bf16 in-register (same RNE values
// as a staged bf16 copy of x).
__device__ __forceinline__ short8 afrag_f32(const float* __restrict__ x, int row, int k0) {
    float4 a = *(const float4*)&x[(size_t)row * 256 + k0];
    float4 b = *(const float4*)&x[(size_t)row * 256 + k0 + 4];
    short8 r = {(short)f2bf(a.x), (short)f2bf(a.y), (short)f2bf(a.z), (short)f2bf(a.w),
                (short)f2bf(b.x), (short)f2bf(b.y), (short)f2bf(b.z), (short)f2bf(b.w)};
    return r;
}

// Cooperative 64-col W-tile load + transpose + bf16 cast into LDS: Bs[c][k].
__device__ __forceinline__ void ldsB(const float* __restrict__ W, int ws, int bn,
                                     unsigned short* __restrict__ Bs) {
    int c4 = (threadIdx.x & 15) * 4;
    int r0 = threadIdx.x >> 4;
    for (int p = 0; p < 16; ++p) {
        int k = p * 16 + r0;
        float4 wv = *(const float4*)&W[(size_t)k * ws + bn + c4];
        Bs[(c4 + 0) * BS_STRIDE + k] = f2bf(wv.x);
        Bs[(c4 + 1) * BS_STRIDE + k] = f2bf(wv.y);
        Bs[(c4 + 2) * BS_STRIDE + k] = f2bf(wv.z);
        Bs[(c4 + 3) * BS_STRIDE + k] = f2bf(wv.w);
    }
    __syncthreads();
}

// ================= K1: segmax+gcw, seg, Q/K/V GEMMs, Hv->vacc2, Tpre =========
// blocks [0,16) segmax+gcw; 16 seg; [17,785) Q/K/V; [785,913) Hv; [913,1169) Tpre
__global__ __launch_bounds__(256) void k1_kernel(
    const float* __restrict__ x,
    const float* __restrict__ Wq, const float* __restrict__ bq,
    const float* __restrict__ Wk, const float* __restrict__ bk,
    const float* __restrict__ Wv, const float* __restrict__ bv,
    const float* __restrict__ Wv1, const float* __restrict__ bv1,
    const float* __restrict__ Wv2, const float* __restrict__ Wc1,
    const float* __restrict__ bc1, const int* __restrict__ batch,
    unsigned short* __restrict__ Qb, unsigned short* __restrict__ Kb,
    unsigned short* __restrict__ Vt, float* __restrict__ vacc2,
    float* __restrict__ Tpre, float* __restrict__ gcw, int* __restrict__ seg) {
    __shared__ __align__(16) char smem[64 * BS_STRIDE * 2];  // 33792 B
    int id = blockIdx.x, tid = threadIdx.x;
    if (id < 16) {  // ---- segmax (4-way row split) + gcw dot for graph id ----
        int g = id;
        int s = seg_search(batch, g), e = seg_search(batch, g + 1);
        float* red = (float*)smem;          // [4][256]
        float* gl  = (float*)smem + 1024;   // [256]
        int c4 = (tid & 63) * 4, way = tid >> 6;
        float4 mx = {-INFINITY, -INFINITY, -INFINITY, -INFINITY};
#pragma unroll 8
        for (int i = s + way; i < e; i += 4) {
            float4 v = *(const float4*)&x[(size_t)i * DIM + c4];
            mx.x = fmaxf(mx.x, v.x); mx.y = fmaxf(mx.y, v.y);
            mx.z = fmaxf(mx.z, v.z); mx.w = fmaxf(mx.w, v.w);
        }
        *(float4*)&red[way * 256 + c4] = mx;
        __syncthreads();
        if (way == 0) {
#pragma unroll
            for (int j = 0; j < 4; ++j) {
                float mm = fmaxf(fmaxf(red[c4 + j], red[256 + c4 + j]),
                                 fmaxf(red[512 + c4 + j], red[768 + c4 + j]));
                gl[c4 + j] = bf2f(f2bf(mm));  // bf16-rounded (consistent precision)
            }
        }
        __syncthreads();
        // 32 loads in flight per batch -> 8 latency exposures instead of 64
        float ac[4] = {0.f, 0.f, 0.f, 0.f};
        for (int kb = 0; kb < 256; kb += 32) {
            float v[32];
#pragma unroll
            for (int j = 0; j < 32; ++j)
                v[j] = Wc1[(size_t)(256 + kb + j) * 256 + tid];
#pragma unroll
            for (int j = 0; j < 32; ++j) ac[j & 3] += gl[kb + j] * v[j];
        }
        gcw[g * 256 + tid] = (ac[0] + ac[1]) + (ac[2] + ac[3]);
        return;
    }
    if (id == 16) {
        if (tid <= NG) seg[tid] = seg_search(batch, tid);
        return;
    }
    int u = id - 17;
    unsigned short* Bs = (unsigned short*)smem;
    int w = tid >> 6, lane = tid & 63, m = lane & 15, quad = lane >> 4;
    if (u < 768) {  // ---- Q/K/V ----
        int z = u >> 8, r = u & 255, bx = r & 63, by = r >> 6;
        const float* W = (z == 0) ? Wq : (z == 1) ? Wk : Wv;
        const float* bias = (z == 0) ? bq : (z == 1) ? bk : bv;
        ldsB(W, 256, by * 64, Bs);
        int rowA = bx * 64 + 16 * w + m;
        short8 a[8];
#pragma unroll
        for (int ks = 0; ks < 8; ++ks) a[ks] = afrag_f32(x, rowA, ks * 32 + quad * 8);
        int node0 = bx * 64 + 16 * w + quad * 4;
#pragma unroll
        for (int nt = 0; nt < 4; ++nt) {
            f32x4 acc = {0.f, 0.f, 0.f, 0.f};
#pragma unroll
            for (int ks = 0; ks < 8; ++ks) {
                short8 b = *(const short8*)&Bs[(nt * 16 + m) * BS_STRIDE + ks * 32 + quad * 8];
                acc = __builtin_amdgcn_mfma_f32_16x16x32_bf16(a[ks], b, acc, 0, 0, 0);
            }
            int col = by * 64 + nt * 16 + m;
            float bb = bias[col];
            if (z == 0) {  // Q pre-scaled by 1/sqrt(64)
#pragma unroll
                for (int r2 = 0; r2 < 4; ++r2)
                    Qb[(size_t)(node0 + r2) * 256 + col] = f2bf((acc[r2] + bb) * 0.125f);
            } else if (z == 1) {
#pragma unroll
                for (int r2 = 0; r2 < 4; ++r2)
                    Kb[(size_t)(node0 + r2) * 256 + col] = f2bf(acc[r2] + bb);
            } else {
                short4_t pk = {(short)f2bf(acc[0] + bb), (short)f2bf(acc[1] + bb),
                               (short)f2bf(acc[2] + bb), (short)f2bf(acc[3] + bb)};
                *(short4_t*)&Vt[(size_t)col * RSLACK + node0] = pk;
            }
        }
    } else if (u < 896) {  // ---- Hv = relu(x@Wv1+bv1)·Wv2 -> vacc2 partial ----
        int r = u - 768, bx = r & 63, by = r >> 6;  // by in {0,1}
        ldsB(Wv1, 128, by * 64, Bs);
        int rowA = bx * 64 + 16 * w + m;
        short8 a[8];
#pragma unroll
        for (int ks = 0; ks < 8; ++ks) a[ks] = afrag_f32(x, rowA, ks * 32 + quad * 8);
        int node0 = bx * 64 + 16 * w + quad * 4;
        float psum[4] = {0.f, 0.f, 0.f, 0.f};
#pragma unroll
        for (int nt = 0; nt < 4; ++nt) {
            f32x4 acc = {0.f, 0.f, 0.f, 0.f};
#pragma unroll
            for (int ks = 0; ks < 8; ++ks) {
                short8 b = *(const short8*)&Bs[(nt * 16 + m) * BS_STRIDE + ks * 32 + quad * 8];
                acc = __builtin_amdgcn_mfma_f32_16x16x32_bf16(a[ks], b, acc, 0, 0, 0);
            }
            int col = by * 64 + nt * 16 + m;
            float bb = bv1[col], wv = Wv2[col];
#pragma unroll
            for (int r2 = 0; r2 < 4; ++r2) psum[r2] += fmaxf(acc[r2] + bb, 0.f) * wv;
        }
#pragma unroll
        for (int r2 = 0; r2 < 4; ++r2) {
#pragma unroll
            for (int mm = 1; mm < 16; mm <<= 1) psum[r2] += __shfl_xor(psum[r2], mm);
            if (m == 0) vacc2[(size_t)(node0 + r2) * 2 + by] = psum[r2];
        }
    } else {  // ---- Tpre = x@Wc1_top + bc1 (f32) ----
        int r = u - 896, bx = r & 63, by = r >> 6;  // by in [0,4)
        ldsB(Wc1, 256, by * 64, Bs);
        int rowA = bx * 64 + 16 * w + m;
        short8 a[8];
#pragma unroll
        for (int ks = 0; ks < 8; ++ks) a[ks] = afrag_f32(x, rowA, ks * 32 + quad * 8);
        int node0 = bx * 64 + 16 * w + quad * 4;
#pragma unroll
        for (int nt = 0; nt < 4; ++nt) {
            f32x4 acc = {0.f, 0.f, 0.f, 0.f};
#pragma unroll
            for (int ks = 0; ks < 8; ++ks) {
                short8 b = *(const short8*)&Bs[(nt * 16 + m) * BS_STRIDE + ks * 32 + quad * 8];
                acc = __builtin_amdgcn_mfma_f32_16x16x32_bf16(a[ks], b, acc, 0, 0, 0);
            }
            int col = by * 64 + nt * 16 + m;
            float bb = bc1[col];
#pragma unroll
            for (int r2 = 0; r2 < 4; ++r2)
                Tpre[(size_t)(node0 + r2) * 256 + col] = acc[r2] + bb;
        }
    }
}

// ================= K2: cooperative LDS-staged attention + cacc ===============
// blocks [0,192): block = (g, qp=32 q rows), 4 waves = 4 heads, K/V chunk
// staged ONCE per block into LDS and reused by 4 heads x 2 q-tiles.
// Each wave walks ALL key chunks -> single O/L (no partials).
// blocks [192,448): cacc
__global__ __launch_bounds__(256) void k2_kernel(
    const float* __restrict__ Tpre, const float* __restrict__ gcw,
    const float* __restrict__ Wc2, const int* __restrict__ batch,
    const unsigned short* __restrict__ Qb, const unsigned short* __restrict__ Kb,
    const unsigned short* __restrict__ Vt, const int* __restrict__ seg,
    unsigned short* __restrict__ Opart, float* __restrict__ Lpart,
    float* __restrict__ cacc) {
    __shared__ __align__(16) unsigned short Ks[64 * BS_STRIDE];      // 33792 B
    __shared__ __align__(16) unsigned short Vs[256 * PS_STRIDE];     // 36864 B
    __shared__ __align__(16) unsigned short Ps[4 * 16 * PS_STRIDE];  // 9216 B
    int tid = threadIdx.x;
    if (blockIdx.x >= K2_ATTN_BLOCKS) {  // ---- cacc: 16 nodes/block ----
        int id2 = blockIdx.x - K2_ATTN_BLOCKS;
        int nl = tid >> 4, cs = (tid & 15) * 16;
        int node = id2 * 16 + nl;
        int g = batch[node];
        float sum = 0.f;
#pragma unroll
        for (int j = 0; j < 16; ++j) {
            int c = cs + j;
            sum += ftanh(Tpre[(size_t)node * 256 + c] + gcw[g * 256 + c]) * Wc2[c];
        }
#pragma unroll
        for (int mm = 1; mm < 16; mm <<= 1) sum += __shfl_xor(sum, mm);
        if ((tid & 15) == 0) cacc[node] = sum;
        return;
    }
    // XCD swizzle: XCD x (blockIdx&7) owns graphs {2x, 2x+1} -> K/V L2-resident
    int xw = blockIdx.x & 7, y = blockIdx.x >> 3;  // y in [0,24)
    int g = xw * 2 + (y >= QP_MAX);
    int qp = (y >= QP_MAX) ? y - QP_MAX : y;
    int w = tid >> 6, lane = tid & 63, m = lane & 15, quad = lane >> 4;
    int h = w;
    int s = seg[g], e = seg[g + 1];
    int q0 = s + qp * 32;
    if (q0 >= e) return;  // uniform across block (depends on g,qp only)

    // Q fragments for this wave's 2 q-tiles (rows have RSLACK slack)
    short8 qa[2][2];
#pragma unroll
    for (int t = 0; t < 2; ++t) {
        qa[t][0] = *(const short8*)&Qb[(size_t)(q0 + t * 16 + m) * 256 + h * 64 + quad * 8];
        qa[t][1] = *(const short8*)&Qb[(size_t)(q0 + t * 16 + m) * 256 + h * 64 + 32 + quad * 8];
    }
    short8 ones = {16256, 16256, 16256, 16256, 16256, 16256, 16256, 16256};  // bf16 1.0
    f32x4 O[2][4];
    f32x4 Lacc[2] = {{0.f, 0.f, 0.f, 0.f}, {0.f, 0.f, 0.f, 0.f}};
#pragma unroll
    for (int t = 0; t < 2; ++t)
#pragma unroll
        for (int nt = 0; nt < 4; ++nt) O[t][nt] = (f32x4){0.f, 0.f, 0.f, 0.f};
    int wbase = w * 16 * PS_STRIDE;
    // staging indices
    int kr = tid >> 2, kc0 = (tid & 3) * 64;          // K: row, col-group
    int voff = (tid & 7) * 8, vdr = tid >> 3;         // V: key-off, d-row base

    for (int kst = s; kst < e; kst += 64) {
        // ---- cooperative stage: K[64 keys][256 d] (coalesced rows) ----
        // jj rotation keeps ds_write_b128 conflict-free across col-groups
        {
            const short8* ksrc = (const short8*)&Kb[(size_t)(kst + kr) * 256 + kc0];
            unsigned short* kdst = &Ks[kr * BS_STRIDE + kc0];
#pragma unroll
            for (int j = 0; j < 8; ++j) {
                int jj = (j + (tid & 3) * 2) & 7;
                *(short8*)&kdst[jj * 8] = ksrc[jj];
            }
        }
        // ---- cooperative stage: V^T[256 d][64 keys] (8 rows/instr) ----
#pragma unroll
        for (int p = 0; p < 8; ++p) {
            int d = p * 32 + vdr;
            *(short8*)&Vs[d * PS_STRIDE + voff] =
                *(const short8*)&Vt[(size_t)d * RSLACK + kst + voff];
        }
        __syncthreads();
#pragma unroll
        for (int t = 0; t < 2; ++t) {
            if (q0 + t * 16 < e) {  // uniform across waves (depends on qp,e)
                f32x4 S[4];
#pragma unroll
                for (int nt = 0; nt < 4; ++nt) {
                    short8 kf0 = *(const short8*)&Ks[(nt * 16 + m) * BS_STRIDE + h * 64 + quad * 8];
                    short8 kf1 = *(const short8*)&Ks[(nt * 16 + m) * BS_STRIDE + h * 64 + 32 + quad * 8];
                    f32x4 sa = {0.f, 0.f, 0.f, 0.f};
                    sa = __builtin_amdgcn_mfma_f32_16x16x32_bf16(qa[t][0], kf0, sa, 0, 0, 0);
                    sa = __builtin_amdgcn_mfma_f32_16x16x32_bf16(qa[t][1], kf1, sa, 0, 0, 0);
                    S[nt] = sa;
                }
                __builtin_amdgcn_wave_barrier();  // don't sink Ps stores above prior Ps reads
#pragma unroll
                for (int nt = 0; nt < 4; ++nt) {
                    bool valid = (kst + nt * 16 + m) < e;
#pragma unroll
                    for (int r3 = 0; r3 < 4; ++r3) {
                        float p = valid ? __expf(S[nt][r3]) : 0.f;  // Q pre-scaled
                        Ps[wbase + (quad * 4 + r3) * PS_STRIDE + nt * 16 + m] = f2bf(p);
                    }
                }
                __builtin_amdgcn_wave_barrier();  // LDS write->read order
                short8 pa0 = *(const short8*)&Ps[wbase + m * PS_STRIDE + quad * 8];
                short8 pa1 = *(const short8*)&Ps[wbase + m * PS_STRIDE + 32 + quad * 8];
                Lacc[t] = __builtin_amdgcn_mfma_f32_16x16x32_bf16(pa0, ones, Lacc[t], 0, 0, 0);
                Lacc[t] = __builtin_amdgcn_mfma_f32_16x16x32_bf16(pa1, ones, Lacc[t], 0, 0, 0);
#pragma unroll
                for (int nt = 0; nt < 4; ++nt) {
                    short8 vf0 = *(const short8*)&Vs[(h * 64 + nt * 16 + m) * PS_STRIDE + quad * 8];
                    short8 vf1 = *(const short8*)&Vs[(h * 64 + nt * 16 + m) * PS_STRIDE + 32 + quad * 8];
                    O[t][nt] = __builtin_amdgcn_mfma_f32_16x16x32_bf16(pa0, vf0, O[t][nt], 0, 0, 0);
                    O[t][nt] = __builtin_amdgcn_mfma_f32_16x16x32_bf16(pa1, vf1, O[t][nt], 0, 0, 0);
                }
            }
        }
        __syncthreads();  // all waves done reading Ks/Vs before next stage
    }
#pragma unroll
    for (int t = 0; t < 2; ++t) {
#pragma unroll
        for (int r3 = 0; r3 < 4; ++r3) {
            int q = q0 + t * 16 + quad * 4 + r3;
            if (q < e) {
                if (m == 0) Lpart[(size_t)q * 4 + h] = Lacc[t][r3];
#pragma unroll
                for (int nt = 0; nt < 4; ++nt)
                    Opart[(size_t)q * 256 + h * 64 + nt * 16 + m] = f2bf(O[t][nt][r3]);
            }
        }
    }
}

// ================= K3: w + graph softmax + combine + residual + LN ===========
// 512 blocks x 8 nodes; per-graph softmax stats computed once per block
__global__ __launch_bounds__(256) void k3_kernel(
    const unsigned short* __restrict__ Opart, const float* __restrict__ Lpart,
    const float* __restrict__ x, const float* __restrict__ vacc2,
    const float* __restrict__ cacc, const float* __restrict__ bv2,
    const float* __restrict__ bc2, const float* __restrict__ gamma,
    const float* __restrict__ beta, const int* __restrict__ batch,
    const int* __restrict__ seg, float* __restrict__ out,
    float* __restrict__ att_out) {
    __shared__ float wsc[776];
    __shared__ float gm[8], gsum[8];
    __shared__ float r1[4], r2[4];
    int tid = threadIdx.x;
    int n0 = blockIdx.x * 8;
    int gf = batch[n0], gl = batch[n0 + 7];
    int s0 = seg[gf], e1 = seg[gl + 1];
    float vb = bv2[0], cb = bc2[0];
    for (int j = s0 + tid; j < e1; j += 256) {
        float2 vv = *(const float2*)&vacc2[(size_t)j * 2];
        wsc[j - s0] = TEMP * (0.6f * fsigmoid(vv.x + vv.y + vb) +
                              0.3f * fsigmoid(cacc[j] + cb) + 0.1f / 4096.f);
    }
    __syncthreads();
    for (int g = gf; g <= gl; ++g) {
        int gs_ = seg[g], ge = seg[g + 1];
        float mx = -1e30f;
        for (int j = gs_ + tid; j < ge; j += 256) mx = fmaxf(mx, wsc[j - s0]);
#pragma unroll
        for (int k2 = 32; k2; k2 >>= 1) mx = fmaxf(mx, __shfl_xor(mx, k2));
        if ((tid & 63) == 0) r1[tid >> 6] = mx;
        __syncthreads();
        mx = fmaxf(fmaxf(r1[0], r1[1]), fmaxf(r1[2], r1[3]));
        float sm = 0.f;
        for (int j = gs_ + tid; j < ge; j += 256) sm += __expf(wsc[j - s0] - mx);
#pragma unroll
        for (int k2 = 32; k2; k2 >>= 1) sm += __shfl_xor(sm, k2);
        __syncthreads();
        if ((tid & 63) == 0) r2[tid >> 6] = sm;
        __syncthreads();
        if (tid == 0) {
            gm[g - gf] = mx;
            gsum[g - gf] = r2[0] + r2[1] + r2[2] + r2[3];
        }
        __syncthreads();
    }
    int h = tid >> 6;
    for (int i = 0; i < 8; ++i) {
        int n = n0 + i;
        int g = batch[n];
        float att_n = __expf(wsc[n - s0] - gm[g - gf]) / gsum[g - gf];
        if (tid == 0) att_out[n] = att_n;
        float L = Lpart[(size_t)n * 4 + h];
        float O = bf2f(Opart[(size_t)n * 256 + tid]);
        float o = (O / L) * att_n + x[(size_t)n * 256 + tid];
        float s1 = o, s2 = o * o;
#pragma unroll
        for (int k2 = 32; k2; k2 >>= 1) {
            s1 += __shfl_xor(s1, k2);
            s2 += __shfl_xor(s2, k2);
        }
        __syncthreads();  // protect r1/r2 reuse across iterations
        if ((tid & 63) == 0) { r1[tid >> 6] = s1; r2[tid >> 6] = s2; }
        __syncthreads();
        float mu = (r1[0] + r1[1] + r1[2] + r1[3]) * (1.f / 256.f);
        float ms = (r2[0] + r2[1] + r2[2] + r2[3]) * (1.f / 256.f);
        float rs = rsqrtf(ms - mu * mu + LN_EPS);
        out[(size_t)n * 256 + tid] = (o - mu) * rs * gamma[tid] + beta[tid];
    }
}

extern "C" void kernel_launch(void* const* d_in, const int* in_sizes, int n_in,
                              void* d_out, int out_size, void* d_ws, size_t ws_size,
                              hipStream_t stream) {
    const float* x     = (const float*)d_in[0];
    const float* Wq    = (const float*)d_in[1];
    const float* bq    = (const float*)d_in[2];
    const float* Wk    = (const float*)d_in[3];
    const float* bk    = (const float*)d_in[4];
    const float* Wv    = (const float*)d_in[5];
    const float* bv    = (const float*)d_in[6];
    const float* Wv1   = (const float*)d_in[7];
    const float* bv1   = (const float*)d_in[8];
    const float* Wv2   = (const float*)d_in[9];
    const float* bv2   = (const float*)d_in[10];
    const float* Wc1   = (const float*)d_in[11];
    const float* bc1   = (const float*)d_in[12];
    const float* Wc2   = (const float*)d_in[13];
    const float* bc2   = (const float*)d_in[14];
    const float* gamma = (const float*)d_in[15];
    const float* beta  = (const float*)d_in[16];
    const int*   batch = (const int*)d_in[17];

    float* out = (float*)d_out;        // [N, D]
    float* att = out + N_NODES * DIM;  // [N]

    // f32 region (all written before read; no zeroing needed)
    float* vacc2 = (float*)d_ws;                        // 4096*2
    float* cacc  = vacc2 + N_NODES * 2;                 // 4096
    float* gcw   = cacc + N_NODES;                      // 16*256
    float* Lpart = gcw + NG * DIM;                      // 4096*4
    float* Tpre  = Lpart + N_NODES * 4;                 // 4096*256
    int*   seg   = (int*)(Tpre + N_NODES * DIM);        // 32 ints
    // bf16 region
    unsigned short* Qb    = (unsigned short*)(seg + 32);  // 4160*256
    unsigned short* Kb    = Qb + RSLACK * DIM;            // 4160*256
    unsigned short* Vt    = Kb + RSLACK * DIM;            // 256*4160
    unsigned short* Opart = Vt + DIM * RSLACK;            // 4096*256

    k1_kernel<<<1169, 256, 0, stream>>>(x, Wq, bq, Wk, bk, Wv, bv, Wv1, bv1, Wv2,
                                        Wc1, bc1, batch, Qb, Kb, Vt, vacc2, Tpre,
                                        gcw, seg);
    k2_kernel<<<K2_ATTN_BLOCKS + 256, 256, 0, stream>>>(Tpre, gcw, Wc2, batch,
                                                        Qb, Kb, Vt, seg,
                                                        Opart, Lpart, cacc);
    k3_kernel<<<N_NODES / 8, 256, 0, stream>>>(Opart, Lpart, x, vacc2, cacc,
                                               bv2, bc2, gamma, beta, batch, seg,
                                               out, att);
}

// Round 5
// 139.728 us; speedup vs baseline: 1.2531x; 1.0101x over previous
//
#include <hip/hip_runtime.h>
#include <math.h>

#define N_NODES 4096
#define DIM 256
#define NH 4
#define NG 16
#define LN_EPS 1e-5f
#define TEMP 5.0f
#define RSLACK 4160     // 4096 + 64 rows of slack for attention tile-tail reads
#define PS_STRIDE 72    // bf16 elems; 144 B row stride, 2-way aliasing only (free)
#define BS_STRIDE 264   // bf16 elems; 528 B row stride -> 2-way-free b128 reads
#define QP_MAX 12       // 12*32 = 384 max rows/graph (qp covers 32 q rows)
#define K2_ATTN_BLOCKS (NG * QP_MAX)  // 192 blocks = 8 XCD * (2 graphs * 12 qp)

typedef __attribute__((ext_vector_type(8))) short short8;
typedef __attribute__((ext_vector_type(4))) short short4_t;
typedef __attribute__((ext_vector_type(4))) float f32x4;

__device__ __forceinline__ unsigned short f2bf(float f) {
    unsigned u = __builtin_bit_cast(unsigned, f);
    u += 0x7FFFu + ((u >> 16) & 1u);  // RNE
    return (unsigned short)(u >> 16);
}
__device__ __forceinline__ float bf2f(unsigned short u) {
    return __builtin_bit_cast(float, (unsigned)u << 16);
}
__device__ __forceinline__ float fsigmoid(float z) { return 1.f / (1.f + __expf(-z)); }
__device__ __forceinline__ float ftanh(float z) {
    float t = __expf(2.f * z);
    return (t - 1.f) / (t + 1.f);
}
__device__ __forceinline__ int seg_search(const int* __restrict__ batch, int g) {
    int lo = 0, hi = N_NODES;
    while (lo < hi) {
        int mid = (lo + hi) >> 1;
        if (batch[mid] < g) lo = mid + 1; else hi = mid;
    }
    return lo;
}

// A-fragment: 8 consecutive k of f32 x, cast bf16 in-register (same RNE values
// as a staged bf16 copy of x).
__device__ __forceinline__ short8 afrag_f32(const float* __restrict__ x, int row, int k0) {
    float4 a = *(const float4*)&x[(size_t)row * 256 + k0];
    float4 b = *(const float4*)&x[(size_t)row * 256 + k0 + 4];
    short8 r = {(short)f2bf(a.x), (short)f2bf(a.y), (short)f2bf(a.z), (short)f2bf(a.w),
                (short)f2bf(b.x), (short)f2bf(b.y), (short)f2bf(b.z), (short)f2bf(b.w)};
    return r;
}

// Cooperative 64-col W-tile load + transpose + bf16 cast into LDS: Bs[c][k].
// Loads batched in 2 rounds of 8 (registers) -> 2 latency exposures, not 16.
__device__ __forceinline__ void ldsB(const float* __restrict__ W, int ws, int bn,
                                     unsigned short* __restrict__ Bs) {
    int c4 = (threadIdx.x & 15) * 4;
    int r0 = threadIdx.x >> 4;
#pragma unroll
    for (int hb = 0; hb < 2; ++hb) {
        float4 wv[8];
#pragma unroll
        for (int p = 0; p < 8; ++p) {
            int k = (hb * 8 + p) * 16 + r0;
            wv[p] = *(const float4*)&W[(size_t)k * ws + bn + c4];
        }
#pragma unroll
        for (int p = 0; p < 8; ++p) {
            int k = (hb * 8 + p) * 16 + r0;
            Bs[(c4 + 0) * BS_STRIDE + k] = f2bf(wv[p].x);
            Bs[(c4 + 1) * BS_STRIDE + k] = f2bf(wv[p].y);
            Bs[(c4 + 2) * BS_STRIDE + k] = f2bf(wv[p].z);
            Bs[(c4 + 3) * BS_STRIDE + k] = f2bf(wv[p].w);
        }
    }
    __syncthreads();
}

// ================= K1: segmax+gcw, seg, Q/K/V GEMMs, Hv->vacc2, Tpre =========
// blocks [0,16) segmax+gcw; 16 seg; [17,785) Q/K/V; [785,913) Hv; [913,1169) Tpre
__global__ __launch_bounds__(256) void k1_kernel(
    const float* __restrict__ x,
    const float* __restrict__ Wq, const float* __restrict__ bq,
    const float* __restrict__ Wk, const float* __restrict__ bk,
    const float* __restrict__ Wv, const float* __restrict__ bv,
    const float* __restrict__ Wv1, const float* __restrict__ bv1,
    const float* __restrict__ Wv2, const float* __restrict__ Wc1,
    const float* __restrict__ bc1, const int* __restrict__ batch,
    unsigned short* __restrict__ Qb, unsigned short* __restrict__ Kb,
    unsigned short* __restrict__ Vt, float* __restrict__ vacc2,
    float* __restrict__ Tpre, float* __restrict__ gcw, int* __restrict__ seg) {
    __shared__ __align__(16) char smem[64 * BS_STRIDE * 2];  // 33792 B
    int id = blockIdx.x, tid = threadIdx.x;
    if (id < 16) {  // ---- segmax (4-way row split) + gcw dot for graph id ----
        int g = id;
        int s = seg_search(batch, g), e = seg_search(batch, g + 1);
        float* red = (float*)smem;          // [4][256]
        float* gl  = (float*)smem + 1024;   // [256]
        int c4 = (tid & 63) * 4, way = tid >> 6;
        float4 mx = {-INFINITY, -INFINITY, -INFINITY, -INFINITY};
#pragma unroll 8
        for (int i = s + way; i < e; i += 4) {
            float4 v = *(const float4*)&x[(size_t)i * DIM + c4];
            mx.x = fmaxf(mx.x, v.x); mx.y = fmaxf(mx.y, v.y);
            mx.z = fmaxf(mx.z, v.z); mx.w = fmaxf(mx.w, v.w);
        }
        *(float4*)&red[way * 256 + c4] = mx;
        __syncthreads();
        if (way == 0) {
#pragma unroll
            for (int j = 0; j < 4; ++j) {
                float mm = fmaxf(fmaxf(red[c4 + j], red[256 + c4 + j]),
                                 fmaxf(red[512 + c4 + j], red[768 + c4 + j]));
                gl[c4 + j] = bf2f(f2bf(mm));  // bf16-rounded (consistent precision)
            }
        }
        __syncthreads();
        // 32 loads in flight per batch -> 8 latency exposures instead of 64
        float ac[4] = {0.f, 0.f, 0.f, 0.f};
        for (int kb = 0; kb < 256; kb += 32) {
            float v[32];
#pragma unroll
            for (int j = 0; j < 32; ++j)
                v[j] = Wc1[(size_t)(256 + kb + j) * 256 + tid];
#pragma unroll
            for (int j = 0; j < 32; ++j) ac[j & 3] += gl[kb + j] * v[j];
        }
        gcw[g * 256 + tid] = (ac[0] + ac[1]) + (ac[2] + ac[3]);
        return;
    }
    if (id == 16) {
        if (tid <= NG) seg[tid] = seg_search(batch, tid);
        return;
    }
    int u = id - 17;
    unsigned short* Bs = (unsigned short*)smem;
    int w = tid >> 6, lane = tid & 63, m = lane & 15, quad = lane >> 4;
    if (u < 768) {  // ---- Q/K/V ----
        int z = u >> 8, r = u & 255, bx = r & 63, by = r >> 6;
        const float* W = (z == 0) ? Wq : (z == 1) ? Wk : Wv;
        const float* bias = (z == 0) ? bq : (z == 1) ? bk : bv;
        ldsB(W, 256, by * 64, Bs);
        int rowA = bx * 64 + 16 * w + m;
        short8 a[8];
#pragma unroll
        for (int ks = 0; ks < 8; ++ks) a[ks] = afrag_f32(x, rowA, ks * 32 + quad * 8);
        int node0 = bx * 64 + 16 * w + quad * 4;
#pragma unroll
        for (int nt = 0; nt < 4; ++nt) {
            f32x4 acc = {0.f, 0.f, 0.f, 0.f};
#pragma unroll
            for (int ks = 0; ks < 8; ++ks) {
                short8 b = *(const short8*)&Bs[(nt * 16 + m) * BS_STRIDE + ks * 32 + quad * 8];
                acc = __builtin_amdgcn_mfma_f32_16x16x32_bf16(a[ks], b, acc, 0, 0, 0);
            }
            int col = by * 64 + nt * 16 + m;
            float bb = bias[col];
            if (z == 0) {  // Q pre-scaled by 1/sqrt(64)
#pragma unroll
                for (int r2 = 0; r2 < 4; ++r2)
                    Qb[(size_t)(node0 + r2) * 256 + col] = f2bf((acc[r2] + bb) * 0.125f);
            } else if (z == 1) {
#pragma unroll
                for (int r2 = 0; r2 < 4; ++r2)
                    Kb[(size_t)(node0 + r2) * 256 + col] = f2bf(acc[r2] + bb);
            } else {
                short4_t pk = {(short)f2bf(acc[0] + bb), (short)f2bf(acc[1] + bb),
                               (short)f2bf(acc[2] + bb), (short)f2bf(acc[3] + bb)};
                *(short4_t*)&Vt[(size_t)col * RSLACK + node0] = pk;
            }
        }
    } else if (u < 896) {  // ---- Hv = relu(x@Wv1+bv1)·Wv2 -> vacc2 partial ----
        int r = u - 768, bx = r & 63, by = r >> 6;  // by in {0,1}
        ldsB(Wv1, 128, by * 64, Bs);
        int rowA = bx * 64 + 16 * w + m;
        short8 a[8];
#pragma unroll
        for (int ks = 0; ks < 8; ++ks) a[ks] = afrag_f32(x, rowA, ks * 32 + quad * 8);
        int node0 = bx * 64 + 16 * w + quad * 4;
        float psum[4] = {0.f, 0.f, 0.f, 0.f};
#pragma unroll
        for (int nt = 0; nt < 4; ++nt) {
            f32x4 acc = {0.f, 0.f, 0.f, 0.f};
#pragma unroll
            for (int ks = 0; ks < 8; ++ks) {
                short8 b = *(const short8*)&Bs[(nt * 16 + m) * BS_STRIDE + ks * 32 + quad * 8];
                acc = __builtin_amdgcn_mfma_f32_16x16x32_bf16(a[ks], b, acc, 0, 0, 0);
            }
            int col = by * 64 + nt * 16 + m;
            float bb = bv1[col], wv = Wv2[col];
#pragma unroll
            for (int r2 = 0; r2 < 4; ++r2) psum[r2] += fmaxf(acc[r2] + bb, 0.f) * wv;
        }
#pragma unroll
        for (int r2 = 0; r2 < 4; ++r2) {
#pragma unroll
            for (int mm = 1; mm < 16; mm <<= 1) psum[r2] += __shfl_xor(psum[r2], mm);
            if (m == 0) vacc2[(size_t)(node0 + r2) * 2 + by] = psum[r2];
        }
    } else {  // ---- Tpre = x@Wc1_top + bc1 (f32) ----
        int r = u - 896, bx = r & 63, by = r >> 6;  // by in [0,4)
        ldsB(Wc1, 256, by * 64, Bs);
        int rowA = bx * 64 + 16 * w + m;
        short8 a[8];
#pragma unroll
        for (int ks = 0; ks < 8; ++ks) a[ks] = afrag_f32(x, rowA, ks * 32 + quad * 8);
        int node0 = bx * 64 + 16 * w + quad * 4;
#pragma unroll
        for (int nt = 0; nt < 4; ++nt) {
            f32x4 acc = {0.f, 0.f, 0.f, 0.f};
#pragma unroll
            for (int ks = 0; ks < 8; ++ks) {
                short8 b = *(const short8*)&Bs[(nt * 16 + m) * BS_STRIDE + ks * 32 + quad * 8];
                acc = __builtin_amdgcn_mfma_f32_16x16x32_bf16(a[ks], b, acc, 0, 0, 0);
            }
            int col = by * 64 + nt * 16 + m;
            float bb = bc1[col];
#pragma unroll
            for (int r2 = 0; r2 < 4; ++r2)
                Tpre[(size_t)(node0 + r2) * 256 + col] = acc[r2] + bb;
        }
    }
}

// ================= K2: cooperative LDS-staged attention + cacc ===============
// blocks [0,192): block = (g, qp=32 q rows), 4 waves = 4 heads; K/V chunk
// staged into LDS once per block; next chunk's loads issued into REGISTERS
// before compute (T14 async-stage split) so HBM latency hides under MFMA.
// blocks [192,448): cacc
__global__ __launch_bounds__(256) void k2_kernel(
    const float* __restrict__ Tpre, const float* __restrict__ gcw,
    const float* __restrict__ Wc2, const int* __restrict__ batch,
    const unsigned short* __restrict__ Qb, const unsigned short* __restrict__ Kb,
    const unsigned short* __restrict__ Vt, const int* __restrict__ seg,
    unsigned short* __restrict__ Opart, float* __restrict__ Lpart,
    float* __restrict__ cacc) {
    __shared__ __align__(16) unsigned short Ks[64 * BS_STRIDE];      // 33792 B
    __shared__ __align__(16) unsigned short Vs[256 * PS_STRIDE];     // 36864 B
    __shared__ __align__(16) unsigned short Ps[4 * 16 * PS_STRIDE];  // 9216 B
    int tid = threadIdx.x;
    if (blockIdx.x >= K2_ATTN_BLOCKS) {  // ---- cacc: 16 nodes/block ----
        int id2 = blockIdx.x - K2_ATTN_BLOCKS;
        int nl = tid >> 4, cs = (tid & 15) * 16;
        int node = id2 * 16 + nl;
        int g = batch[node];
        float sum = 0.f;
#pragma unroll
        for (int j = 0; j < 16; ++j) {
            int c = cs + j;
            sum += ftanh(Tpre[(size_t)node * 256 + c] + gcw[g * 256 + c]) * Wc2[c];
        }
#pragma unroll
        for (int mm = 1; mm < 16; mm <<= 1) sum += __shfl_xor(sum, mm);
        if ((tid & 15) == 0) cacc[node] = sum;
        return;
    }
    // XCD swizzle: XCD x (blockIdx&7) owns graphs {2x, 2x+1} -> K/V L2-resident
    int xw = blockIdx.x & 7, y = blockIdx.x >> 3;  // y in [0,24)
    int g = xw * 2 + (y >= QP_MAX);
    int qp = (y >= QP_MAX) ? y - QP_MAX : y;
    int w = tid >> 6, lane = tid & 63, m = lane & 15, quad = lane >> 4;
    int h = w;
    int s = seg[g], e = seg[g + 1];
    int q0 = s + qp * 32;
    if (q0 >= e) return;  // uniform across block (depends on g,qp only)

    // Q fragments for this wave's 2 q-tiles (rows have RSLACK slack)
    short8 qa[2][2];
#pragma unroll
    for (int t = 0; t < 2; ++t) {
        qa[t][0] = *(const short8*)&Qb[(size_t)(q0 + t * 16 + m) * 256 + h * 64 + quad * 8];
        qa[t][1] = *(const short8*)&Qb[(size_t)(q0 + t * 16 + m) * 256 + h * 64 + 32 + quad * 8];
    }
    short8 ones = {16256, 16256, 16256, 16256, 16256, 16256, 16256, 16256};  // bf16 1.0
    f32x4 O[2][4];
    f32x4 Lacc[2] = {{0.f, 0.f, 0.f, 0.f}, {0.f, 0.f, 0.f, 0.f}};
#pragma unroll
    for (int t = 0; t < 2; ++t)
#pragma unroll
        for (int nt = 0; nt < 4; ++nt) O[t][nt] = (f32x4){0.f, 0.f, 0.f, 0.f};
    int wbase = w * 16 * PS_STRIDE;
    // staging indices
    int kr = tid >> 2, kc0 = (tid & 3) * 64;          // K: row, col-group
    int voff = (tid & 7) * 8, vdr = tid >> 3;         // V: key-off, d-row base

    // T14 split: issue loads into regs, commit to LDS later
    short8 kpre[8], vpre[8];
    {
        const short8* ksrc = (const short8*)&Kb[(size_t)(s + kr) * 256 + kc0];
#pragma unroll
        for (int j = 0; j < 8; ++j) kpre[j] = ksrc[j];
#pragma unroll
        for (int p = 0; p < 8; ++p) {
            int d = p * 32 + vdr;
            vpre[p] = *(const short8*)&Vt[(size_t)d * RSLACK + s + voff];
        }
    }
    {
        unsigned short* kdst = &Ks[kr * BS_STRIDE + kc0];
#pragma unroll
        for (int j = 0; j < 8; ++j) *(short8*)&kdst[j * 8] = kpre[j];
#pragma unroll
        for (int p = 0; p < 8; ++p) {
            int d = p * 32 + vdr;
            *(short8*)&Vs[d * PS_STRIDE + voff] = vpre[p];
        }
    }
    __syncthreads();

    for (int kst = s; kst < e; kst += 64) {
        bool hasnext = (kst + 64) < e;  // uniform across block
        if (hasnext) {  // issue next chunk's loads; latency hides under compute
            const short8* ksrc = (const short8*)&Kb[(size_t)(kst + 64 + kr) * 256 + kc0];
#pragma unroll
            for (int j = 0; j < 8; ++j) kpre[j] = ksrc[j];
#pragma unroll
            for (int p = 0; p < 8; ++p) {
                int d = p * 32 + vdr;
                vpre[p] = *(const short8*)&Vt[(size_t)d * RSLACK + kst + 64 + voff];
            }
        }
#pragma unroll
        for (int t = 0; t < 2; ++t) {
            if (q0 + t * 16 < e) {  // uniform across waves (depends on qp,e)
                f32x4 S[4];
#pragma unroll
                for (int nt = 0; nt < 4; ++nt) {
                    short8 kf0 = *(const short8*)&Ks[(nt * 16 + m) * BS_STRIDE + h * 64 + quad * 8];
                    short8 kf1 = *(const short8*)&Ks[(nt * 16 + m) * BS_STRIDE + h * 64 + 32 + quad * 8];
                    f32x4 sa = {0.f, 0.f, 0.f, 0.f};
                    sa = __builtin_amdgcn_mfma_f32_16x16x32_bf16(qa[t][0], kf0, sa, 0, 0, 0);
                    sa = __builtin_amdgcn_mfma_f32_16x16x32_bf16(qa[t][1], kf1, sa, 0, 0, 0);
                    S[nt] = sa;
                }
                __builtin_amdgcn_wave_barrier();  // don't sink Ps stores above prior Ps reads
#pragma unroll
                for (int nt = 0; nt < 4; ++nt) {
                    bool valid = (kst + nt * 16 + m) < e;
#pragma unroll
                    for (int r3 = 0; r3 < 4; ++r3) {
                        float p = valid ? __expf(S[nt][r3]) : 0.f;  // Q pre-scaled
                        Ps[wbase + (quad * 4 + r3) * PS_STRIDE + nt * 16 + m] = f2bf(p);
                    }
                }
                __builtin_amdgcn_wave_barrier();  // LDS write->read order
                short8 pa0 = *(const short8*)&Ps[wbase + m * PS_STRIDE + quad * 8];
                short8 pa1 = *(const short8*)&Ps[wbase + m * PS_STRIDE + 32 + quad * 8];
                Lacc[t] = __builtin_amdgcn_mfma_f32_16x16x32_bf16(pa0, ones, Lacc[t], 0, 0, 0);
                Lacc[t] = __builtin_amdgcn_mfma_f32_16x16x32_bf16(pa1, ones, Lacc[t], 0, 0, 0);
#pragma unroll
                for (int nt = 0; nt < 4; ++nt) {
                    short8 vf0 = *(const short8*)&Vs[(h * 64 + nt * 16 + m) * PS_STRIDE + quad * 8];
                    short8 vf1 = *(const short8*)&Vs[(h * 64 + nt * 16 + m) * PS_STRIDE + 32 + quad * 8];
                    O[t][nt] = __builtin_amdgcn_mfma_f32_16x16x32_bf16(pa0, vf0, O[t][nt], 0, 0, 0);
                    O[t][nt] = __builtin_amdgcn_mfma_f32_16x16x32_bf16(pa1, vf1, O[t][nt], 0, 0, 0);
                }
            }
        }
        if (hasnext) {  // commit prefetched chunk to LDS (both syncs uniform)
            __syncthreads();  // all waves done reading Ks/Vs
            unsigned short* kdst = &Ks[kr * BS_STRIDE + kc0];
#pragma unroll
            for (int j = 0; j < 8; ++j) *(short8*)&kdst[j * 8] = kpre[j];
#pragma unroll
            for (int p = 0; p < 8; ++p) {
                int d = p * 32 + vdr;
                *(short8*)&Vs[d * PS_STRIDE + voff] = vpre[p];
            }
            __syncthreads();  // staged chunk visible to all waves
        }
    }
#pragma unroll
    for (int t = 0; t < 2; ++t) {
#pragma unroll
        for (int r3 = 0; r3 < 4; ++r3) {
            int q = q0 + t * 16 + quad * 4 + r3;
            if (q < e) {
                if (m == 0) Lpart[(size_t)q * 4 + h] = Lacc[t][r3];
#pragma unroll
                for (int nt = 0; nt < 4; ++nt)
                    Opart[(size_t)q * 256 + h * 64 + nt * 16 + m] = f2bf(O[t][nt][r3]);
            }
        }
    }
}

// ================= K3: w + graph softmax + combine + residual + LN ===========
// 512 blocks x 8 nodes; stats per block, then one WAVE per node (no syncs in
// the LN phase: 64 lanes x 4 cols, pure shuffle reductions)
__global__ __launch_bounds__(256) void k3_kernel(
    const unsigned short* __restrict__ Opart, const float* __restrict__ Lpart,
    const float* __restrict__ x, const float* __restrict__ vacc2,
    const float* __restrict__ cacc, const float* __restrict__ bv2,
    const float* __restrict__ bc2, const float* __restrict__ gamma,
    const float* __restrict__ beta, const int* __restrict__ batch,
    const int* __restrict__ seg, float* __restrict__ out,
    float* __restrict__ att_out) {
    __shared__ float wsc[776];
    __shared__ float gm[8], gsum[8];
    __shared__ float r1[4], r2[4];
    int tid = threadIdx.x;
    int n0 = blockIdx.x * 8;
    int gf = batch[n0], gl = batch[n0 + 7];
    int s0 = seg[gf], e1 = seg[gl + 1];
    float vb = bv2[0], cb = bc2[0];
    for (int j = s0 + tid; j < e1; j += 256) {
        float2 vv = *(const float2*)&vacc2[(size_t)j * 2];
        wsc[j - s0] = TEMP * (0.6f * fsigmoid(vv.x + vv.y + vb) +
                              0.3f * fsigmoid(cacc[j] + cb) + 0.1f / 4096.f);
    }
    __syncthreads();
    for (int g = gf; g <= gl; ++g) {  // <=2 iterations (8 nodes span <=2 graphs)
        int gs_ = seg[g], ge = seg[g + 1];
        float mx = -1e30f;
        for (int j = gs_ + tid; j < ge; j += 256) mx = fmaxf(mx, wsc[j - s0]);
#pragma unroll
        for (int k2 = 32; k2; k2 >>= 1) mx = fmaxf(mx, __shfl_xor(mx, k2));
        if ((tid & 63) == 0) r1[tid >> 6] = mx;
        __syncthreads();
        mx = fmaxf(fmaxf(r1[0], r1[1]), fmaxf(r1[2], r1[3]));
        float sm = 0.f;
        for (int j = gs_ + tid; j < ge; j += 256) sm += __expf(wsc[j - s0] - mx);
#pragma unroll
        for (int k2 = 32; k2; k2 >>= 1) sm += __shfl_xor(sm, k2);
        __syncthreads();
        if ((tid & 63) == 0) r2[tid >> 6] = sm;
        __syncthreads();
        if (tid == 0) {
            gm[g - gf] = mx;
            gsum[g - gf] = r2[0] + r2[1] + r2[2] + r2[3];
        }
        __syncthreads();
    }
    // ---- wave-per-node LN: wave w handles nodes n0+2w, n0+2w+1 ----
    int w = tid >> 6, lane = tid & 63;
    int c0 = lane * 4;
#pragma unroll
    for (int i = 0; i < 2; ++i) {
        int n = n0 + w * 2 + i;
        int g = batch[n];
        float att_n = __expf(wsc[n - s0] - gm[g - gf]) / gsum[g - gf];
        if (lane == 0) att_out[n] = att_n;
        float L = Lpart[(size_t)n * 4 + (c0 >> 6)];
        short4_t ov = *(const short4_t*)&Opart[(size_t)n * 256 + c0];
        float4 xv = *(const float4*)&x[(size_t)n * 256 + c0];
        float o0 = (bf2f((unsigned short)ov[0]) / L) * att_n + xv.x;
        float o1 = (bf2f((unsigned short)ov[1]) / L) * att_n + xv.y;
        float o2 = (bf2f((unsigned short)ov[2]) / L) * att_n + xv.z;
        float o3 = (bf2f((unsigned short)ov[3]) / L) * att_n + xv.w;
        float s1 = (o0 + o1) + (o2 + o3);
        float s2 = (o0 * o0 + o1 * o1) + (o2 * o2 + o3 * o3);
#pragma unroll
        for (int k2 = 32; k2; k2 >>= 1) {
            s1 += __shfl_xor(s1, k2);
            s2 += __shfl_xor(s2, k2);
        }
        float mu = s1 * (1.f / 256.f);
        float ms = s2 * (1.f / 256.f);
        float rs = rsqrtf(ms - mu * mu + LN_EPS);
        float4 gv = *(const float4*)&gamma[c0];
        float4 bvv = *(const float4*)&beta[c0];
        float4 ov4 = {(o0 - mu) * rs * gv.x + bvv.x, (o1 - mu) * rs * gv.y + bvv.y,
                      (o2 - mu) * rs * gv.z + bvv.z, (o3 - mu) * rs * gv.w + bvv.w};
        *(float4*)&out[(size_t)n * 256 + c0] = ov4;
    }
}

extern "C" void kernel_launch(void* const* d_in, const int* in_sizes, int n_in,
                              void* d_out, int out_size, void* d_ws, size_t ws_size,
                              hipStream_t stream) {
    const float* x     = (const float*)d_in[0];
    const float* Wq    = (const float*)d_in[1];
    const float* bq    = (const float*)d_in[2];
    const float* Wk    = (const float*)d_in[3];
    const float* bk    = (const float*)d_in[4];
    const float* Wv    = (const float*)d_in[5];
    const float* bv    = (const float*)d_in[6];
    const float* Wv1   = (const float*)d_in[7];
    const float* bv1   = (const float*)d_in[8];
    const float* Wv2   = (const float*)d_in[9];
    const float* bv2   = (const float*)d_in[10];
    const float* Wc1   = (const float*)d_in[11];
    const float* bc1   = (const float*)d_in[12];
    const float* Wc2   = (const float*)d_in[13];
    const float* bc2   = (const float*)d_in[14];
    const float* gamma = (const float*)d_in[15];
    const float* beta  = (const float*)d_in[16];
    const int*   batch = (const int*)d_in[17];

    float* out = (float*)d_out;        // [N, D]
    float* att = out + N_NODES * DIM;  // [N]

    // f32 region (all written before read; no zeroing needed)
    float* vacc2 = (float*)d_ws;                        // 4096*2
    float* cacc  = vacc2 + N_NODES * 2;                 // 4096
    float* gcw   = cacc + N_NODES;                      // 16*256
    float* Lpart = gcw + NG * DIM;                      // 4096*4
    float* Tpre  = Lpart + N_NODES * 4;                 // 4096*256
    int*   seg   = (int*)(Tpre + N_NODES * DIM);        // 32 ints
    // bf16 region
    unsigned short* Qb    = (unsigned short*)(seg + 32);  // 4160*256
    unsigned short* Kb    = Qb + RSLACK * DIM;            // 4160*256
    unsigned short* Vt    = Kb + RSLACK * DIM;            // 256*4160
    unsigned short* Opart = Vt + DIM * RSLACK;            // 4096*256

    k1_kernel<<<1169, 256, 0, stream>>>(x, Wq, bq, Wk, bk, Wv, bv, Wv1, bv1, Wv2,
                                        Wc1, bc1, batch, Qb, Kb, Vt, vacc2, Tpre,
                                        gcw, seg);
    k2_kernel<<<K2_ATTN_BLOCKS + 256, 256, 0, stream>>>(Tpre, gcw, Wc2, batch,
                                                        Qb, Kb, Vt, seg,
                                                        Opart, Lpart, cacc);
    k3_kernel<<<N_NODES / 8, 256, 0, stream>>>(Opart, Lpart, x, vacc2, cacc,
                                               bv2, bc2, gamma, beta, batch, seg,
                                               out, att);
}